// Round 8
// baseline (1758.750 us; speedup 1.0000x reference)
//
#include <hip/hip_runtime.h>
#include <hip/hip_bf16.h>

typedef unsigned short ushort_t;
typedef unsigned int uint_t;
typedef unsigned char uchar_t;

constexpr int OBS  = 25;
constexpr int HID  = 128;
constexpr int EMB  = 64;
constexpr int CAT  = 136;   // 2*EMB + EDGE_DIM
constexpr int NN   = 50000;
constexpr int NPB  = 7;     // nodes per edge-block (mean 112 edges/block)

// MFMA edge-kernel geometry
constexpr int TE      = 128;          // edge-tile rows
constexpr int ETHR    = 256;          // 4 waves
constexpr int K1PAD   = 148;          // cat K padded (136 -> 144 used, 148 stride)
constexpr int K2PAD   = 140;          // hid K stride (128 used)
constexpr int K1STEPS = 9;            // 9*16 = 144
constexpr int K2STEPS = 8;            // 8*16 = 128

// node-kernel geometry
constexpr int TB = 128;

typedef __attribute__((ext_vector_type(8)))  short bf16x8;
typedef __attribute__((ext_vector_type(16))) float f32x16;
typedef __attribute__((ext_vector_type(4)))  uint_t uint4v;
typedef __attribute__((ext_vector_type(4)))  float f32x4;

__device__ __forceinline__ ushort_t f2bf(float f) {
    union { float f; uint_t u; } v; v.f = f;
    uint_t r = v.u + 0x7FFFu + ((v.u >> 16) & 1u);   // RNE
    return (ushort_t)(r >> 16);
}

__device__ __forceinline__ bf16x8 ld8(const ushort_t* p) {
    uint2 lo = *reinterpret_cast<const uint2*>(p);
    uint2 hi = *reinterpret_cast<const uint2*>(p + 4);
    uint4 u = make_uint4(lo.x, lo.y, hi.x, hi.y);
    return __builtin_bit_cast(bf16x8, u);
}

// C-fragment row map for 32x32x16 (HW-verified): col = l31 within 32-col tile,
// row = 4*lhi + (r&3) + 8*(r>>2) within the 32-row sub-tile.
#define CROW(R, LHI) (4 * (LHI) + ((R) & 3) + 8 * ((R) >> 2))

// ================= counting sort of edges by dst =================
__global__ __launch_bounds__(256) void k_hist(
    const int* __restrict__ dst, int* __restrict__ hist, int ne)
{
    int e = blockIdx.x * 256 + threadIdx.x;
    if (e < ne) atomicAdd(&hist[dst[e]], 1);
}

__global__ __launch_bounds__(512) void k_scan1(
    const int* __restrict__ hist, int* __restrict__ scanned,
    int* __restrict__ bsum, int nk)
{
    __shared__ int s[512];
    int t = threadIdx.x, i = blockIdx.x * 512 + t;
    int v = (i < nk) ? hist[i] : 0;
    s[t] = v; __syncthreads();
#pragma unroll
    for (int off = 1; off < 512; off <<= 1) {
        int x = (t >= off) ? s[t - off] : 0;
        __syncthreads();
        s[t] += x;
        __syncthreads();
    }
    if (i < nk) scanned[i] = s[t] - v;          // exclusive within block
    if (t == 511) bsum[blockIdx.x] = s[511];
}

// merged scan2+scan3; also writes the preserved rowptr copy
__global__ __launch_bounds__(512) void k_scan3(
    int* __restrict__ scanned, const int* __restrict__ bsum,
    int* __restrict__ rowptr, int nk, int ne)
{
    __shared__ int pref;
    if (threadIdx.x == 0) {
        int run = 0;
        for (int b = 0; b < (int)blockIdx.x; ++b) run += bsum[b];
        pref = run;
    }
    __syncthreads();
    int i = blockIdx.x * 512 + threadIdx.x;
    if (i < nk) {
        int v = scanned[i] + pref;
        scanned[i] = v;          // mutable cursor for scatter
        rowptr[i] = v;           // preserved CSR rowptr
    }
    if (blockIdx.x == 0 && threadIdx.x == 0) rowptr[nk] = ne;
}

// scatter edges into dst-sorted order; 16B/edge: [dn|rxn, ryn|selfflag, src, dst]
__global__ __launch_bounds__(256) void k_scatter_feat(
    const float* __restrict__ pos, const int* __restrict__ src,
    const int* __restrict__ dst, int* __restrict__ ofs,
    uint4v* __restrict__ eab4, int ne)
{
    int e = blockIdx.x * 256 + threadIdx.x;
    if (e >= ne) return;
    int s = src[e], d = dst[e];
    float rx = pos[d * 2 + 0] - pos[s * 2 + 0];
    float ry = pos[d * 2 + 1] - pos[s * 2 + 1];
    float dist = sqrtf(rx * rx + ry * ry);
    float inv = 1.f / (dist + 1e-6f);
    float dn = dist * (1.f / 1500.f);
    uint_t ux = (uint_t)f2bf(dn) | ((uint_t)f2bf(rx * inv) << 16);
    uint_t uy = (uint_t)f2bf(ry * inv) | ((dist > 0.f ? 0u : 1u) << 16);
    int p = atomicAdd(&ofs[d], 1);
    uint4v ev = { ux, uy, (uint_t)s, (uint_t)d };
    __builtin_nontemporal_store(ev, eab4 + p);
}

// ================= weight prep: bf16 transposed W1T/W2T =================
__global__ __launch_bounds__(256) void k_prep(
    const float* __restrict__ w1, const float* __restrict__ w2,
    ushort_t* __restrict__ w1t, ushort_t* __restrict__ w2t)
{
    int t = blockIdx.x * 256 + threadIdx.x;
    const int n1 = 3 * HID * K1PAD;          // [l][c][k]
    if (t < n1) {
        int l = t / (HID * K1PAD), rem = t % (HID * K1PAD);
        int c = rem / K1PAD, k = rem % K1PAD;
        float v = (k < CAT) ? w1[(size_t)l * CAT * HID + (size_t)k * HID + c] : 0.f;
        w1t[t] = f2bf(v);
    }
    const int n2 = 3 * EMB * K2PAD;          // [l][c][k]
    if (t < n2) {
        int l = t / (EMB * K2PAD), rem = t % (EMB * K2PAD);
        int c = rem / K2PAD, k = rem % K2PAD;
        float v = (k < HID) ? w2[(size_t)l * HID * EMB + (size_t)k * EMB + c] : 0.f;
        w2t[t] = f2bf(v);
    }
}

// ================= MFMA encoder =================
constexpr int EKP = 36;
__global__ __launch_bounds__(256, 1) void k_encoder_mfma(
    const float* __restrict__ obs,
    const float* __restrict__ w1, const float* __restrict__ b1,
    const float* __restrict__ lng, const float* __restrict__ lnb,
    const float* __restrict__ w2, const float* __restrict__ b2,
    float* __restrict__ x, ushort_t* __restrict__ xb, int n)
{
    __shared__ __align__(16) ushort_t s_OB[TB * EKP];
    __shared__ __align__(16) ushort_t s_B1[HID * EKP];
    __shared__ __align__(16) float    s_G[TB * 132];
    __shared__ __align__(16) ushort_t s_H[TB * K2PAD];
    __shared__ __align__(16) ushort_t s_W2[EMB * K2PAD];

    const int tid = threadIdx.x;
    const int lane = tid & 63, wid = tid >> 6;
    const int wr = wid >> 1, wc = wid & 1;
    const int l31 = lane & 31, lhi = lane >> 5;
    const int n0 = blockIdx.x * TB;

    for (int i = tid; i < TB * 32; i += 256) {
        int row = i >> 5, k = i & 31;
        int gn = n0 + row;
        float v = (gn < n && k < OBS) ? obs[(size_t)gn * OBS + k] : 0.f;
        s_OB[row * EKP + k] = f2bf(v);
    }
    for (int i = tid; i < 32 * HID; i += 256) {
        int k = i >> 7, c = i & 127;
        float v = (k < OBS) ? w1[k * HID + c] : 0.f;
        s_B1[c * EKP + k] = f2bf(v);
    }
    __syncthreads();

    f32x16 a00, a01, a10, a11;
    {
        float bv0 = b1[wc * 64 + l31], bv1 = b1[wc * 64 + 32 + l31];
#pragma unroll
        for (int i = 0; i < 16; ++i) { a00[i] = bv0; a01[i] = bv1; a10[i] = bv0; a11[i] = bv1; }
    }
    {
        const ushort_t* aR0 = s_OB + (wr * 64 + l31) * EKP;
        const ushort_t* aR1 = aR0 + 32 * EKP;
        const ushort_t* bR0 = s_B1 + (wc * 64 + l31) * EKP;
        const ushort_t* bR1 = bR0 + 32 * EKP;
        const int koff = lhi * 8;
#pragma unroll
        for (int s = 0; s < 2; ++s) {
            const int ke = s * 16 + koff;
            bf16x8 av0 = ld8(aR0 + ke), av1 = ld8(aR1 + ke);
            bf16x8 bv0 = ld8(bR0 + ke), bv1 = ld8(bR1 + ke);
            a00 = __builtin_amdgcn_mfma_f32_32x32x16_bf16(av0, bv0, a00, 0, 0, 0);
            a01 = __builtin_amdgcn_mfma_f32_32x32x16_bf16(av0, bv1, a01, 0, 0, 0);
            a10 = __builtin_amdgcn_mfma_f32_32x32x16_bf16(av1, bv0, a10, 0, 0, 0);
            a11 = __builtin_amdgcn_mfma_f32_32x32x16_bf16(av1, bv1, a11, 0, 0, 0);
        }
    }
#define WRITE_G(ACC, SUB, NC)                                                  \
    {                                                                          \
        const int col = wc * 64 + (NC) * 32 + l31;                             \
        _Pragma("unroll")                                                      \
        for (int r = 0; r < 16; ++r) {                                         \
            int row = wr * 64 + (SUB) * 32 + CROW(r, lhi);                     \
            s_G[row * 132 + col] = ACC[r];                                     \
        }                                                                      \
    }
    WRITE_G(a00, 0, 0) WRITE_G(a01, 0, 1) WRITE_G(a10, 1, 0) WRITE_G(a11, 1, 1)
#undef WRITE_G
    __syncthreads();

    for (int i = tid; i < HID * EMB; i += 256) {
        int k = i >> 6, c = i & 63;
        s_W2[c * K2PAD + k] = f2bf(w2[i]);
    }
    if (tid < TB) {
        float sum = 0.f, sum2 = 0.f;
        const float* gr = s_G + tid * 132;
#pragma unroll 8
        for (int q = 0; q < HID; ++q) { float v = gr[q]; sum += v; sum2 += v * v; }
        float mu = sum * (1.f / HID);
        float var = fmaxf(sum2 * (1.f / HID) - mu * mu, 0.f);
        float rs = 1.f / sqrtf(var + 1e-5f);
        ushort_t* hr = s_H + tid * K2PAD;
#pragma unroll 8
        for (int q = 0; q < HID; ++q) {
            float v = (gr[q] - mu) * rs * lng[q] + lnb[q];
            hr[q] = f2bf(fmaxf(v, 0.f));
        }
    }
    __syncthreads();

    f32x16 c0, c1;
    {
        float bv = b2[wc * 32 + l31];
#pragma unroll
        for (int i = 0; i < 16; ++i) { c0[i] = bv; c1[i] = bv; }
    }
    {
        const ushort_t* aR0 = s_H + (wr * 64 + l31) * K2PAD;
        const ushort_t* aR1 = aR0 + 32 * K2PAD;
        const ushort_t* bR = s_W2 + (wc * 32 + l31) * K2PAD;
        const int koff = lhi * 8;
#pragma unroll
        for (int s = 0; s < K2STEPS; ++s) {
            const int ke = s * 16 + koff;
            bf16x8 av0 = ld8(aR0 + ke), av1 = ld8(aR1 + ke);
            bf16x8 bv = ld8(bR + ke);
            c0 = __builtin_amdgcn_mfma_f32_32x32x16_bf16(av0, bv, c0, 0, 0, 0);
            c1 = __builtin_amdgcn_mfma_f32_32x32x16_bf16(av1, bv, c1, 0, 0, 0);
        }
    }
    {
        const int col = wc * 32 + l31;
#define STORE_X(CC, SUB)                                                       \
        {                                                                      \
            _Pragma("unroll")                                                  \
            for (int r = 0; r < 16; ++r) {                                     \
                int row = wr * 64 + (SUB) * 32 + CROW(r, lhi);                 \
                int gn = n0 + row;                                             \
                if (gn < n) {                                                  \
                    float v = fmaxf(CC[r], 0.f);                               \
                    x[(size_t)gn * EMB + col] = v;                             \
                    xb[(size_t)gn * EMB + col] = f2bf(v);                      \
                }                                                              \
            }                                                                  \
        }
        STORE_X(c0, 0) STORE_X(c1, 1)
#undef STORE_X
    }
}

// ================= MFMA edge layer (node-aligned, ZERO global atomics) ======
// Each block owns NPB=7 consecutive nodes and loops over <=128-edge tiles of
// their contiguous (dst-sorted) edge range. Messages seg-reduce into an LDS
// accumulator; aggr written once per node with plain coalesced stores.
__global__ __launch_bounds__(ETHR, 4) void k_edge_mfma(
    const ushort_t* __restrict__ xb,
    const uint4v* __restrict__ eab4,    // sorted: [dn|rxn, ryn|flag, src, dst]
    const int* __restrict__ rowptr,     // CSR rowptr [NN+1]
    const ushort_t* __restrict__ w1t,   // [128][148] bf16
    const float* __restrict__ b1,
    const ushort_t* __restrict__ w2t,   // [64][140] bf16
    const float* __restrict__ b2,
    float* __restrict__ aggr, int nwg)
{
    __shared__ __align__(16) ushort_t s_A[TE * K1PAD];   // 37888 B; H/M overlay
    __shared__ float   s_acc[8 * 64];                    //  2048 B (row 7 = trash)
    __shared__ uchar_t s_ld[TE];                         //   128 B local dst 0..7
    ushort_t* s_H = s_A;                                 // [128][140] bf16 phase 2
    float*    s_M = reinterpret_cast<float*>(s_A);       // [128][68] fp32 phase 3

    const int tid  = threadIdx.x;
    const int lane = tid & 63, wid = tid >> 6;
    const int wr = wid >> 1, wc = wid & 1;
    const int l31 = lane & 31, lhi = lane >> 5;

    // bijective XCD swizzle over node-blocks
    const int q = nwg >> 3, rr = nwg & 7;
    const int bid = blockIdx.x;
    const int xcd = bid & 7, loc = bid >> 3;
    const int swz = (xcd < rr ? xcd * (q + 1) : rr * (q + 1) + (xcd - rr) * q) + loc;

    const int n0 = swz * NPB;
    const int n1 = min(n0 + NPB, NN);
    const int eb0 = rowptr[n0];
    const int ee  = rowptr[n1];

    for (int i = tid; i < 8 * 64; i += ETHR) s_acc[i] = 0.f;

    for (int eb = eb0; eb < ee; eb += TE) {
        // ---- gather tile: [x[dst] | x[src] | feat | 0pad] ----
        {
            const int e = tid >> 1, h = tid & 1, ge = eb + e;
            ushort_t* arow = s_A + e * K1PAD;
            if (ge < ee) {
                uint4v ev = eab4[ge];
                if (h == 0) {
                    s_ld[e] = (uchar_t)((int)ev.w - n0);
                    const uint2* sp = reinterpret_cast<const uint2*>(xb + (size_t)ev.w * EMB);
                    uint2* dp = reinterpret_cast<uint2*>(arow);
#pragma unroll
                    for (int i = 0; i < 16; ++i) dp[i] = sp[i];
                } else {
                    const uint2* sp = reinterpret_cast<const uint2*>(xb + (size_t)ev.z * EMB);
                    uint2* dp = reinterpret_cast<uint2*>(arow + EMB);
#pragma unroll
                    for (int i = 0; i < 16; ++i) dp[i] = sp[i];
                    uint_t dn_b = ev.x & 0xFFFFu, rxn_b = ev.x >> 16;
                    uint_t ryn_b = ev.y & 0xFFFFu, flag = ev.y >> 16;
                    uint_t cos_b = flag ? 0x3F80u : rxn_b;   // dist==0 -> cos=1,sin=0
                    uint_t sin_b = flag ? 0u : ryn_b;
                    union { uint_t u; float f; } cv; cv.u = dn_b << 16;
                    uint_t dn2_b = (uint_t)f2bf(cv.f * cv.f);
                    uint2* ap = reinterpret_cast<uint2*>(arow + 2 * EMB);
                    ap[0] = make_uint2(dn_b | (rxn_b << 16), ryn_b | (cos_b << 16));
                    ap[1] = make_uint2(sin_b | (dn2_b << 16), 0u);
                    uint2* pp = reinterpret_cast<uint2*>(arow + CAT);
                    pp[0] = make_uint2(0u, 0u); pp[1] = make_uint2(0u, 0u);
                    pp[2] = make_uint2(0u, 0u);
                }
            } else {
                const uint2 z = make_uint2(0u, 0u);
                if (h == 0) {
                    s_ld[e] = 7;                         // dummy -> trash row
                    uint2* dp = reinterpret_cast<uint2*>(arow);
#pragma unroll
                    for (int i = 0; i < 16; ++i) dp[i] = z;
                } else {
                    uint2* dp = reinterpret_cast<uint2*>(arow + EMB);
#pragma unroll
                    for (int i = 0; i < 16; ++i) dp[i] = z;
                    uint2* ap = reinterpret_cast<uint2*>(arow + 2 * EMB);
                    ap[0] = z; ap[1] = z;
                    uint2* pp = reinterpret_cast<uint2*>(arow + CAT);
                    pp[0] = z; pp[1] = z; pp[2] = z;
                }
            }
        }
        __syncthreads();

        // ---- GEMM1: [128 x 144] @ [144 x 128]; B from global (L2-hot) ----
        f32x16 a00, a01, a10, a11;
        {
            float bv0 = b1[wc * 64 + l31], bv1 = b1[wc * 64 + 32 + l31];
#pragma unroll
            for (int i = 0; i < 16; ++i) { a00[i] = bv0; a01[i] = bv1; a10[i] = bv0; a11[i] = bv1; }
        }
        {
            const ushort_t* aR0 = s_A + (wr * 64 + l31) * K1PAD;
            const ushort_t* aR1 = aR0 + 32 * K1PAD;
            const ushort_t* bR0 = w1t + (wc * 64 + l31) * K1PAD;
            const ushort_t* bR1 = bR0 + 32 * K1PAD;
            const int koff = lhi * 8;
#pragma unroll
            for (int s = 0; s < K1STEPS; ++s) {
                const int ke = s * 16 + koff;
                bf16x8 av0 = ld8(aR0 + ke);
                bf16x8 av1 = ld8(aR1 + ke);
                bf16x8 bv0 = ld8(bR0 + ke);
                bf16x8 bv1 = ld8(bR1 + ke);
                a00 = __builtin_amdgcn_mfma_f32_32x32x16_bf16(av0, bv0, a00, 0, 0, 0);
                a01 = __builtin_amdgcn_mfma_f32_32x32x16_bf16(av0, bv1, a01, 0, 0, 0);
                a10 = __builtin_amdgcn_mfma_f32_32x32x16_bf16(av1, bv0, a10, 0, 0, 0);
                a11 = __builtin_amdgcn_mfma_f32_32x32x16_bf16(av1, bv1, a11, 0, 0, 0);
            }
        }
        __syncthreads();

        // ---- relu -> bf16 H (overlay) ----
#define WRITE_H(ACC, SUB, NC)                                                  \
        {                                                                      \
            const int col = wc * 64 + (NC) * 32 + l31;                         \
            _Pragma("unroll")                                                  \
            for (int r = 0; r < 16; ++r) {                                     \
                int row = wr * 64 + (SUB) * 32 + CROW(r, lhi);                 \
                s_H[row * K2PAD + col] = f2bf(fmaxf(ACC[r], 0.f));             \
            }                                                                  \
        }
        WRITE_H(a00, 0, 0) WRITE_H(a01, 0, 1) WRITE_H(a10, 1, 0) WRITE_H(a11, 1, 1)
#undef WRITE_H
        __syncthreads();

        // ---- GEMM2: [128 x 128] @ [128 x 64]; B from global ----
        f32x16 c0, c1;
        {
            float bv = b2[wc * 32 + l31];
#pragma unroll
            for (int i = 0; i < 16; ++i) { c0[i] = bv; c1[i] = bv; }
        }
        {
            const ushort_t* aR0 = s_H + (wr * 64 + l31) * K2PAD;
            const ushort_t* aR1 = aR0 + 32 * K2PAD;
            const ushort_t* bR = w2t + (wc * 32 + l31) * K2PAD;
            const int koff = lhi * 8;
#pragma unroll
            for (int s = 0; s < K2STEPS; ++s) {
                const int ke = s * 16 + koff;
                bf16x8 av0 = ld8(aR0 + ke);
                bf16x8 av1 = ld8(aR1 + ke);
                bf16x8 bv = ld8(bR + ke);
                c0 = __builtin_amdgcn_mfma_f32_32x32x16_bf16(av0, bv, c0, 0, 0, 0);
                c1 = __builtin_amdgcn_mfma_f32_32x32x16_bf16(av1, bv, c1, 0, 0, 0);
            }
        }
        __syncthreads();   // H reads done before M overlay

        // ---- messages (x0.25 attention constant) -> fp32 LDS [128][68] ----
        {
            const int col = wc * 32 + l31;
#pragma unroll
            for (int r = 0; r < 16; ++r) {
                int row = wr * 64 + CROW(r, lhi);
                s_M[row * 68 + col] = c0[r] * 0.25f;
                s_M[(row + 32) * 68 + col] = c1[r] * 0.25f;
            }
        }
        __syncthreads();

        // ---- seg-reduce 32-row groups into LDS accumulator (LDS atomics) ----
        {
            const int col = tid & 63, g = tid >> 6, base = g * 32;
            int cur = s_ld[base];
            float accv = 0.f;
#pragma unroll 8
            for (int r = 0; r < 32; ++r) {
                int d = s_ld[base + r];
                float v = s_M[(base + r) * 68 + col];
                if (d != cur) {                       // wave-uniform
                    atomicAdd(&s_acc[cur * 64 + col], accv);
                    accv = 0.f; cur = d;
                }
                accv += v;
            }
            atomicAdd(&s_acc[cur * 64 + col], accv);
        }
        __syncthreads();   // before next tile overwrites s_A / s_M
    }

    // ---- write aggr once per node: plain coalesced stores, no atomics ----
    for (int i = tid; i < NPB * 64; i += ETHR) {
        int r = i >> 6, c = i & 63;
        int gn = n0 + r;
        if (gn < NN) aggr[(size_t)gn * EMB + c] = s_acc[r * 64 + c];
    }
}

// ================= MFMA node update =================
__global__ __launch_bounds__(256, 2) void k_update_mfma(
    float* __restrict__ x, ushort_t* __restrict__ xb,
    const float* __restrict__ aggr,
    const float* __restrict__ w1, const float* __restrict__ b1,
    const float* __restrict__ w2, const float* __restrict__ b2,
    const float* __restrict__ g, const float* __restrict__ bb, int n)
{
    __shared__ __align__(16) ushort_t s_A[TB * K2PAD];
    __shared__ __align__(16) ushort_t s_B[TB * K2PAD];
    ushort_t* s_H  = s_A;
    ushort_t* s_W2 = s_B;
    float*    s_U  = reinterpret_cast<float*>(s_B);

    const int tid = threadIdx.x;
    const int lane = tid & 63, wid = tid >> 6;
    const int wr = wid >> 1, wc = wid & 1;
    const int l31 = lane & 31, lhi = lane >> 5;
    const int n0 = blockIdx.x * TB;

    {
        const int row = tid >> 1, h = tid & 1;
        const int gn = n0 + row;
        ushort_t* arow = s_A + row * K2PAD;
        if (h == 0) {
            uint2* dp = reinterpret_cast<uint2*>(arow);
            if (gn < n) {
                const uint2* sp = reinterpret_cast<const uint2*>(xb + (size_t)gn * EMB);
#pragma unroll
                for (int i = 0; i < 16; ++i) dp[i] = sp[i];
            } else {
                const uint2 z = make_uint2(0u, 0u);
#pragma unroll
                for (int i = 0; i < 16; ++i) dp[i] = z;
            }
        } else {
            if (gn < n) {
                const f32x4* sp = reinterpret_cast<const f32x4*>(aggr + (size_t)gn * EMB);
#pragma unroll
                for (int i = 0; i < 16; ++i) {
                    f32x4 v = __builtin_nontemporal_load(sp + i);
                    ushort_t* qq = arow + EMB + i * 4;
                    qq[0] = f2bf(v.x); qq[1] = f2bf(v.y); qq[2] = f2bf(v.z); qq[3] = f2bf(v.w);
                }
            } else {
#pragma unroll
                for (int i = 0; i < 16; ++i) {
                    ushort_t* qq = arow + EMB + i * 4;
                    qq[0] = 0; qq[1] = 0; qq[2] = 0; qq[3] = 0;
                }
            }
        }
    }
    for (int i = tid; i < 128 * 128; i += 256) {
        int k = i >> 7, c = i & 127;
        s_B[c * K2PAD + k] = f2bf(w1[i]);
    }
    __syncthreads();

    f32x16 a00, a01, a10, a11;
    {
        float bv0 = b1[wc * 64 + l31], bv1 = b1[wc * 64 + 32 + l31];
#pragma unroll
        for (int i = 0; i < 16; ++i) { a00[i] = bv0; a01[i] = bv1; a10[i] = bv0; a11[i] = bv1; }
    }
    {
        const ushort_t* aR0 = s_A + (wr * 64 + l31) * K2PAD;
        const ushort_t* aR1 = aR0 + 32 * K2PAD;
        const ushort_t* bR0 = s_B + (wc * 64 + l31) * K2PAD;
        const ushort_t* bR1 = bR0 + 32 * K2PAD;
        const int koff = lhi * 8;
#pragma unroll
        for (int s = 0; s < K2STEPS; ++s) {
            const int ke = s * 16 + koff;
            bf16x8 av0 = ld8(aR0 + ke), av1 = ld8(aR1 + ke);
            bf16x8 bv0 = ld8(bR0 + ke), bv1 = ld8(bR1 + ke);
            a00 = __builtin_amdgcn_mfma_f32_32x32x16_bf16(av0, bv0, a00, 0, 0, 0);
            a01 = __builtin_amdgcn_mfma_f32_32x32x16_bf16(av0, bv1, a01, 0, 0, 0);
            a10 = __builtin_amdgcn_mfma_f32_32x32x16_bf16(av1, bv0, a10, 0, 0, 0);
            a11 = __builtin_amdgcn_mfma_f32_32x32x16_bf16(av1, bv1, a11, 0, 0, 0);
        }
    }
    __syncthreads();

#define WRITE_H(ACC, SUB, NC)                                                  \
    {                                                                          \
        const int col = wc * 64 + (NC) * 32 + l31;                             \
        _Pragma("unroll")                                                      \
        for (int r = 0; r < 16; ++r) {                                         \
            int row = wr * 64 + (SUB) * 32 + CROW(r, lhi);                     \
            s_H[row * K2PAD + col] = f2bf(fmaxf(ACC[r], 0.f));                 \
        }                                                                      \
    }
    WRITE_H(a00, 0, 0) WRITE_H(a01, 0, 1) WRITE_H(a10, 1, 0) WRITE_H(a11, 1, 1)
#undef WRITE_H
    for (int i = tid; i < HID * EMB; i += 256) {
        int k = i >> 6, c = i & 63;
        s_W2[c * K2PAD + k] = f2bf(w2[i]);
    }
    __syncthreads();

    f32x16 c0, c1;
    {
        float bv = b2[wc * 32 + l31];
#pragma unroll
        for (int i = 0; i < 16; ++i) { c0[i] = bv; c1[i] = bv; }
    }
    {
        const ushort_t* aR0 = s_H + (wr * 64 + l31) * K2PAD;
        const ushort_t* aR1 = aR0 + 32 * K2PAD;
        const ushort_t* bR = s_W2 + (wc * 32 + l31) * K2PAD;
        const int koff = lhi * 8;
#pragma unroll
        for (int s = 0; s < K2STEPS; ++s) {
            const int ke = s * 16 + koff;
            bf16x8 av0 = ld8(aR0 + ke), av1 = ld8(aR1 + ke);
            bf16x8 bv = ld8(bR + ke);
            c0 = __builtin_amdgcn_mfma_f32_32x32x16_bf16(av0, bv, c0, 0, 0, 0);
            c1 = __builtin_amdgcn_mfma_f32_32x32x16_bf16(av1, bv, c1, 0, 0, 0);
        }
    }
    __syncthreads();

    {
        const int col = wc * 32 + l31;
#pragma unroll
        for (int r = 0; r < 16; ++r) {
            int row = wr * 64 + CROW(r, lhi);
            s_U[row * 68 + col] = c0[r];
            s_U[(row + 32) * 68 + col] = c1[r];
        }
    }
    __syncthreads();

    if (tid < TB) {
        int gn = n0 + tid;
        if (gn < n) {
            const float* xr = x + (size_t)gn * EMB;
            float* ur = s_U + tid * 68;
            float sum = 0.f, sum2 = 0.f;
#pragma unroll 8
            for (int q = 0; q < EMB; ++q) {
                float v = xr[q] + ur[q];
                ur[q] = v;
                sum += v; sum2 += v * v;
            }
            float mu = sum * (1.f / EMB);
            float var = fmaxf(sum2 * (1.f / EMB) - mu * mu, 0.f);
            float rs = 1.f / sqrtf(var + 1e-5f);
            float* xo = x + (size_t)gn * EMB;
            ushort_t* xbo = xb + (size_t)gn * EMB;
#pragma unroll 8
            for (int q = 0; q < EMB; ++q) {
                float v = (ur[q] - mu) * rs * g[q] + bb[q];
                xo[q] = v;
                xbo[q] = f2bf(v);
            }
        }
    }
}

// ================= MFMA output projection =================
constexpr int OKP = 68;
__global__ __launch_bounds__(256, 2) void k_output_mfma(
    const ushort_t* __restrict__ xb,
    const float* __restrict__ w1, const float* __restrict__ b1,
    const float* __restrict__ w2, const float* __restrict__ b2,
    float* __restrict__ out, int n)
{
    __shared__ __align__(16) ushort_t s_A[TB * OKP];
    __shared__ __align__(16) ushort_t s_B[HID * OKP];
    __shared__ __align__(16) ushort_t s_H[TB * K2PAD];
    __shared__ __align__(16) ushort_t s_W2[EMB * K2PAD];

    const int tid = threadIdx.x;
    const int lane = tid & 63, wid = tid >> 6;
    const int wr = wid >> 1, wc = wid & 1;
    const int l31 = lane & 31, lhi = lane >> 5;
    const int n0 = blockIdx.x * TB;

    for (int i = tid; i < TB * 16; i += 256) {
        int row = i >> 4, q = i & 15;
        int gn = n0 + row;
        uint2 v = make_uint2(0u, 0u);
        if (gn < n) v = reinterpret_cast<const uint2*>(xb + (size_t)gn * EMB)[q];
        *reinterpret_cast<uint2*>(s_A + row * OKP + q * 4) = v;
    }
    for (int i = tid; i < EMB * HID; i += 256) {
        int k = i >> 7, c = i & 127;
        s_B[c * OKP + k] = f2bf(w1[i]);
    }
    for (int i = tid; i < HID * EMB; i += 256) {
        int k = i >> 6, c = i & 63;
        s_W2[c * K2PAD + k] = f2bf(w2[i]);
    }
    __syncthreads();

    f32x16 a00, a01, a10, a11;
    {
        float bv0 = b1[wc * 64 + l31], bv1 = b1[wc * 64 + 32 + l31];
#pragma unroll
        for (int i = 0; i < 16; ++i) { a00[i] = bv0; a01[i] = bv1; a10[i] = bv0; a11[i] = bv1; }
    }
    {
        const ushort_t* aR0 = s_A + (wr * 64 + l31) * OKP;
        const ushort_t* aR1 = aR0 + 32 * OKP;
        const ushort_t* bR0 = s_B + (wc * 64 + l31) * OKP;
        const ushort_t* bR1 = bR0 + 32 * OKP;
        const int koff = lhi * 8;
#pragma unroll
        for (int s = 0; s < 4; ++s) {
            const int ke = s * 16 + koff;
            bf16x8 av0 = ld8(aR0 + ke), av1 = ld8(aR1 + ke);
            bf16x8 bv0 = ld8(bR0 + ke), bv1 = ld8(bR1 + ke);
            a00 = __builtin_amdgcn_mfma_f32_32x32x16_bf16(av0, bv0, a00, 0, 0, 0);
            a01 = __builtin_amdgcn_mfma_f32_32x32x16_bf16(av0, bv1, a01, 0, 0, 0);
            a10 = __builtin_amdgcn_mfma_f32_32x32x16_bf16(av1, bv0, a10, 0, 0, 0);
            a11 = __builtin_amdgcn_mfma_f32_32x32x16_bf16(av1, bv1, a11, 0, 0, 0);
        }
    }
    __syncthreads();

#define WRITE_H(ACC, SUB, NC)                                                  \
    {                                                                          \
        const int col = wc * 64 + (NC) * 32 + l31;                             \
        _Pragma("unroll")                                                      \
        for (int r = 0; r < 16; ++r) {                                         \
            int row = wr * 64 + (SUB) * 32 + CROW(r, lhi);                     \
            s_H[row * K2PAD + col] = f2bf(fmaxf(ACC[r], 0.f));                 \
        }                                                                      \
    }
    WRITE_H(a00, 0, 0) WRITE_H(a01, 0, 1) WRITE_H(a10, 1, 0) WRITE_H(a11, 1, 1)
#undef WRITE_H
    __syncthreads();

    f32x16 c0, c1;
    {
        float bv = b2[wc * 32 + l31];
#pragma unroll
        for (int i = 0; i < 16; ++i) { c0[i] = bv; c1[i] = bv; }
    }
    {
        const ushort_t* aR0 = s_H + (wr * 64 + l31) * K2PAD;
        const ushort_t* aR1 = aR0 + 32 * K2PAD;
        const ushort_t* bR = s_W2 + (wc * 32 + l31) * K2PAD;
        const int koff = lhi * 8;
#pragma unroll
        for (int s = 0; s < K2STEPS; ++s) {
            const int ke = s * 16 + koff;
            bf16x8 av0 = ld8(aR0 + ke), av1 = ld8(aR1 + ke);
            bf16x8 bv = ld8(bR + ke);
            c0 = __builtin_amdgcn_mfma_f32_32x32x16_bf16(av0, bv, c0, 0, 0, 0);
            c1 = __builtin_amdgcn_mfma_f32_32x32x16_bf16(av1, bv, c1, 0, 0, 0);
        }
    }
    {
        const int col = wc * 32 + l31;
#pragma unroll
        for (int r = 0; r < 16; ++r) {
            int row0 = wr * 64 + CROW(r, lhi);
            int g0 = n0 + row0, g1 = g0 + 32;
            if (g0 < n) out[(size_t)g0 * EMB + col] = c0[r];
            if (g1 < n) out[(size_t)g1 * EMB + col] = c1[r];
        }
    }
}

extern "C" void kernel_launch(void* const* d_in, const int* in_sizes, int n_in,
                              void* d_out, int out_size, void* d_ws, size_t ws_size,
                              hipStream_t stream)
{
    const float* obs     = (const float*)d_in[0];
    const float* pos     = (const float*)d_in[1];
    const int*   eidx    = (const int*)d_in[2];
    const float* enc_w1  = (const float*)d_in[3];
    const float* enc_b1  = (const float*)d_in[4];
    const float* enc_lng = (const float*)d_in[5];
    const float* enc_lnb = (const float*)d_in[6];
    const float* enc_w2  = (const float*)d_in[7];
    const float* enc_b2  = (const float*)d_in[8];
    const float* msg_w1  = (const float*)d_in[9];
    const float* msg_b1  = (const float*)d_in[10];
    const float* msg_w2  = (const float*)d_in[11];
    const float* msg_b2  = (const float*)d_in[12];
    // d_in[13..16] = att_* : mathematically unused (mean(softmax) == 0.25)
    const float* upd_w1  = (const float*)d_in[17];
    const float* upd_b1  = (const float*)d_in[18];
    const float* upd_w2  = (const float*)d_in[19];
    const float* upd_b2  = (const float*)d_in[20];
    const float* ln_g    = (const float*)d_in[21];
    const float* ln_b    = (const float*)d_in[22];
    const float* out_w1  = (const float*)d_in[23];
    const float* out_b1  = (const float*)d_in[24];
    const float* out_w2  = (const float*)d_in[25];
    const float* out_b2  = (const float*)d_in[26];

    const int n  = in_sizes[0] / OBS;   // 50000
    const int ne = in_sizes[2] / 2;     // 800000
    const int* src = eidx;
    const int* dst = eidx + ne;

    char* ws = (char*)d_ws;
    float*    x      = (float*)ws;                         // 12,800,000 B
    ushort_t* xbuf   = (ushort_t*)(ws + 12800000);         //  6,400,000 B
    uint4v*   eab4   = (uint4v*)(ws + 19200000);           // 12,800,000 B (sorted)
    float*    aggr   = (float*)(ws + 32000000);            // 12,800,000 B
    ushort_t* w1t    = (ushort_t*)(ws + 44800000);         //    113,664 B
    ushort_t* w2t    = (ushort_t*)(ws + 44913664);         //     53,760 B
    int*      hist   = (int*)(ws + 44967424);              //    200,000 B
    int*      scan   = (int*)(ws + 45167424);              //    200,000 B
    int*      rowptr = (int*)(ws + 45367424);              //    200,004 B
    int*      bsum   = (int*)(ws + 45567432);              //        512 B
    // total ~45.6 MB (< 51.2 MB proven safe)

    const int NB1 = (NN + 511) / 512;     // 98
    const int nb  = (n + TB - 1) / TB;    // 391
    const int nbe = (NN + NPB - 1) / NPB; // 7143 node-blocks

    // ---- counting sort of edges by dst (+ fused edge features, rowptr) ----
    hipMemsetAsync(hist, 0, NN * sizeof(int), stream);
    k_hist<<<(ne + 255) / 256, 256, 0, stream>>>(dst, hist, ne);
    k_scan1<<<NB1, 512, 0, stream>>>(hist, scan, bsum, NN);
    k_scan3<<<NB1, 512, 0, stream>>>(scan, bsum, rowptr, NN, ne);
    k_scatter_feat<<<(ne + 255) / 256, 256, 0, stream>>>(pos, src, dst, scan,
                                                         eab4, ne);

    k_prep<<<(3 * HID * K1PAD + 255) / 256, 256, 0, stream>>>(msg_w1, msg_w2, w1t, w2t);
    k_encoder_mfma<<<nb, 256, 0, stream>>>(obs, enc_w1, enc_b1, enc_lng, enc_lnb,
                                           enc_w2, enc_b2, x, xbuf, n);

    for (int l = 0; l < 3; ++l) {
        k_edge_mfma<<<nbe, ETHR, 0, stream>>>(
            xbuf, eab4, rowptr,
            w1t + (size_t)l * HID * K1PAD, msg_b1 + (size_t)l * HID,
            w2t + (size_t)l * EMB * K2PAD, msg_b2 + (size_t)l * EMB,
            aggr, nbe);
        k_update_mfma<<<nb, 256, 0, stream>>>(
            x, xbuf, aggr,
            upd_w1 + (size_t)l * 2 * EMB * HID, upd_b1 + (size_t)l * HID,
            upd_w2 + (size_t)l * HID * EMB, upd_b2 + (size_t)l * EMB,
            ln_g + (size_t)l * EMB, ln_b + (size_t)l * EMB, n);
    }
    k_output_mfma<<<nb, 256, 0, stream>>>(
        xbuf, out_w1, out_b1, out_w2, out_b2, (float*)d_out, n);
}

// Round 9
// 754.947 us; speedup vs baseline: 2.3296x; 2.3296x over previous
//
#include <hip/hip_runtime.h>
#include <hip/hip_bf16.h>

typedef unsigned short ushort_t;
typedef unsigned int uint_t;

constexpr int OBS  = 25;
constexpr int HID  = 128;
constexpr int EMB  = 64;
constexpr int CAT  = 136;   // 2*EMB + EDGE_DIM
constexpr int NN   = 50000;

// MFMA edge-kernel geometry (r5 proven best: 151us, 0 bank conflicts, 4 blk/CU)
constexpr int TE      = 128;          // edges per block (800000 % 128 == 0)
constexpr int ETHR    = 256;          // 4 waves
constexpr int K1PAD   = 148;          // cat K padded (136 -> 144 used, 148 stride)
constexpr int K2PAD   = 140;          // hid K stride (128 used)
constexpr int K1STEPS = 9;            // 9*16 = 144
constexpr int K2STEPS = 8;            // 8*16 = 128

// node-kernel geometry
constexpr int TB = 128;

typedef __attribute__((ext_vector_type(8)))  short bf16x8;
typedef __attribute__((ext_vector_type(16))) float f32x16;
typedef __attribute__((ext_vector_type(4)))  uint_t uint4v;

__device__ __forceinline__ ushort_t f2bf(float f) {
    union { float f; uint_t u; } v; v.f = f;
    uint_t r = v.u + 0x7FFFu + ((v.u >> 16) & 1u);   // RNE
    return (ushort_t)(r >> 16);
}

__device__ __forceinline__ bf16x8 ld8(const ushort_t* p) {
    uint2 lo = *reinterpret_cast<const uint2*>(p);
    uint2 hi = *reinterpret_cast<const uint2*>(p + 4);
    uint4 u = make_uint4(lo.x, lo.y, hi.x, hi.y);
    return __builtin_bit_cast(bf16x8, u);
}

// C-fragment row map for 32x32x16 (HW-verified): col = l31 within 32-col tile,
// row = 4*lhi + (r&3) + 8*(r>>2) within the 32-row sub-tile.
#define CROW(R, LHI) (4 * (LHI) + ((R) & 3) + 8 * ((R) >> 2))

// ================= counting sort of edges by dst =================
__global__ __launch_bounds__(256) void k_hist(
    const int* __restrict__ dst, int* __restrict__ hist, int ne)
{
    int e = blockIdx.x * 256 + threadIdx.x;
    if (e < ne) atomicAdd(&hist[dst[e]], 1);
}

__global__ __launch_bounds__(512) void k_scan1(
    const int* __restrict__ hist, int* __restrict__ scanned,
    int* __restrict__ bsum, int nk)
{
    __shared__ int s[512];
    int t = threadIdx.x, i = blockIdx.x * 512 + t;
    int v = (i < nk) ? hist[i] : 0;
    s[t] = v; __syncthreads();
#pragma unroll
    for (int off = 1; off < 512; off <<= 1) {
        int x = (t >= off) ? s[t - off] : 0;
        __syncthreads();
        s[t] += x;
        __syncthreads();
    }
    if (i < nk) scanned[i] = s[t] - v;          // exclusive within block
    if (t == 511) bsum[blockIdx.x] = s[511];
}

// merged scan2+scan3: each block computes its bsum prefix locally
__global__ __launch_bounds__(512) void k_scan3(
    int* __restrict__ scanned, const int* __restrict__ bsum, int nk)
{
    __shared__ int pref;
    if (threadIdx.x == 0) {
        int run = 0;
        for (int b = 0; b < (int)blockIdx.x; ++b) run += bsum[b];
        pref = run;
    }
    __syncthreads();
    int i = blockIdx.x * 512 + threadIdx.x;
    if (i < nk) scanned[i] += pref;
}

// scatter edges into dst-sorted order; 16B/edge: [dn|rxn, ryn|selfflag, src, dst]
// cos/sin/dn^2 reconstructed in the edge kernel (cos==rxn, sin==ryn in bf16
// except dist==0, where cos=1,sin=0 -> flag).
__global__ __launch_bounds__(256) void k_scatter_feat(
    const float* __restrict__ pos, const int* __restrict__ src,
    const int* __restrict__ dst, int* __restrict__ ofs,
    uint4v* __restrict__ eab4, int ne)
{
    int e = blockIdx.x * 256 + threadIdx.x;
    if (e >= ne) return;
    int s = src[e], d = dst[e];
    float rx = pos[d * 2 + 0] - pos[s * 2 + 0];
    float ry = pos[d * 2 + 1] - pos[s * 2 + 1];
    float dist = sqrtf(rx * rx + ry * ry);
    float inv = 1.f / (dist + 1e-6f);
    float dn = dist * (1.f / 1500.f);
    uint_t ux = (uint_t)f2bf(dn) | ((uint_t)f2bf(rx * inv) << 16);
    uint_t uy = (uint_t)f2bf(ry * inv) | ((dist > 0.f ? 0u : 1u) << 16);
    int p = atomicAdd(&ofs[d], 1);
    uint4v ev = { ux, uy, (uint_t)s, (uint_t)d };
    eab4[p] = ev;
}

// ================= weight prep: bf16 transposed W1T/W2T =================
__global__ __launch_bounds__(256) void k_prep(
    const float* __restrict__ w1, const float* __restrict__ w2,
    ushort_t* __restrict__ w1t, ushort_t* __restrict__ w2t)
{
    int t = blockIdx.x * 256 + threadIdx.x;
    const int n1 = 3 * HID * K1PAD;          // [l][c][k]
    if (t < n1) {
        int l = t / (HID * K1PAD), rem = t % (HID * K1PAD);
        int c = rem / K1PAD, k = rem % K1PAD;
        float v = (k < CAT) ? w1[(size_t)l * CAT * HID + (size_t)k * HID + c] : 0.f;
        w1t[t] = f2bf(v);
    }
    const int n2 = 3 * EMB * K2PAD;          // [l][c][k]
    if (t < n2) {
        int l = t / (EMB * K2PAD), rem = t % (EMB * K2PAD);
        int c = rem / K2PAD, k = rem % K2PAD;
        float v = (k < HID) ? w2[(size_t)l * HID * EMB + (size_t)k * EMB + c] : 0.f;
        w2t[t] = f2bf(v);
    }
}

// ================= MFMA encoder =================
constexpr int EKP = 36;
__global__ __launch_bounds__(256, 1) void k_encoder_mfma(
    const float* __restrict__ obs,
    const float* __restrict__ w1, const float* __restrict__ b1,
    const float* __restrict__ lng, const float* __restrict__ lnb,
    const float* __restrict__ w2, const float* __restrict__ b2,
    float* __restrict__ x, ushort_t* __restrict__ xb, int n)
{
    __shared__ __align__(16) ushort_t s_OB[TB * EKP];
    __shared__ __align__(16) ushort_t s_B1[HID * EKP];
    __shared__ __align__(16) float    s_G[TB * 132];
    __shared__ __align__(16) ushort_t s_H[TB * K2PAD];
    __shared__ __align__(16) ushort_t s_W2[EMB * K2PAD];

    const int tid = threadIdx.x;
    const int lane = tid & 63, wid = tid >> 6;
    const int wr = wid >> 1, wc = wid & 1;
    const int l31 = lane & 31, lhi = lane >> 5;
    const int n0 = blockIdx.x * TB;

    for (int i = tid; i < TB * 32; i += 256) {
        int row = i >> 5, k = i & 31;
        int gn = n0 + row;
        float v = (gn < n && k < OBS) ? obs[(size_t)gn * OBS + k] : 0.f;
        s_OB[row * EKP + k] = f2bf(v);
    }
    for (int i = tid; i < 32 * HID; i += 256) {
        int k = i >> 7, c = i & 127;
        float v = (k < OBS) ? w1[k * HID + c] : 0.f;
        s_B1[c * EKP + k] = f2bf(v);
    }
    __syncthreads();

    f32x16 a00, a01, a10, a11;
    {
        float bv0 = b1[wc * 64 + l31], bv1 = b1[wc * 64 + 32 + l31];
#pragma unroll
        for (int i = 0; i < 16; ++i) { a00[i] = bv0; a01[i] = bv1; a10[i] = bv0; a11[i] = bv1; }
    }
    {
        const ushort_t* aR0 = s_OB + (wr * 64 + l31) * EKP;
        const ushort_t* aR1 = aR0 + 32 * EKP;
        const ushort_t* bR0 = s_B1 + (wc * 64 + l31) * EKP;
        const ushort_t* bR1 = bR0 + 32 * EKP;
        const int koff = lhi * 8;
#pragma unroll
        for (int s = 0; s < 2; ++s) {
            const int ke = s * 16 + koff;
            bf16x8 av0 = ld8(aR0 + ke), av1 = ld8(aR1 + ke);
            bf16x8 bv0 = ld8(bR0 + ke), bv1 = ld8(bR1 + ke);
            a00 = __builtin_amdgcn_mfma_f32_32x32x16_bf16(av0, bv0, a00, 0, 0, 0);
            a01 = __builtin_amdgcn_mfma_f32_32x32x16_bf16(av0, bv1, a01, 0, 0, 0);
            a10 = __builtin_amdgcn_mfma_f32_32x32x16_bf16(av1, bv0, a10, 0, 0, 0);
            a11 = __builtin_amdgcn_mfma_f32_32x32x16_bf16(av1, bv1, a11, 0, 0, 0);
        }
    }
#define WRITE_G(ACC, SUB, NC)                                                  \
    {                                                                          \
        const int col = wc * 64 + (NC) * 32 + l31;                             \
        _Pragma("unroll")                                                      \
        for (int r = 0; r < 16; ++r) {                                         \
            int row = wr * 64 + (SUB) * 32 + CROW(r, lhi);                     \
            s_G[row * 132 + col] = ACC[r];                                     \
        }                                                                      \
    }
    WRITE_G(a00, 0, 0) WRITE_G(a01, 0, 1) WRITE_G(a10, 1, 0) WRITE_G(a11, 1, 1)
#undef WRITE_G
    __syncthreads();

    for (int i = tid; i < HID * EMB; i += 256) {
        int k = i >> 6, c = i & 63;
        s_W2[c * K2PAD + k] = f2bf(w2[i]);
    }
    if (tid < TB) {
        float sum = 0.f, sum2 = 0.f;
        const float* gr = s_G + tid * 132;
#pragma unroll 8
        for (int q = 0; q < HID; ++q) { float v = gr[q]; sum += v; sum2 += v * v; }
        float mu = sum * (1.f / HID);
        float var = fmaxf(sum2 * (1.f / HID) - mu * mu, 0.f);
        float rs = 1.f / sqrtf(var + 1e-5f);
        ushort_t* hr = s_H + tid * K2PAD;
#pragma unroll 8
        for (int q = 0; q < HID; ++q) {
            float v = (gr[q] - mu) * rs * lng[q] + lnb[q];
            hr[q] = f2bf(fmaxf(v, 0.f));
        }
    }
    __syncthreads();

    f32x16 c0, c1;
    {
        float bv = b2[wc * 32 + l31];
#pragma unroll
        for (int i = 0; i < 16; ++i) { c0[i] = bv; c1[i] = bv; }
    }
    {
        const ushort_t* aR0 = s_H + (wr * 64 + l31) * K2PAD;
        const ushort_t* aR1 = aR0 + 32 * K2PAD;
        const ushort_t* bR = s_W2 + (wc * 32 + l31) * K2PAD;
        const int koff = lhi * 8;
#pragma unroll
        for (int s = 0; s < K2STEPS; ++s) {
            const int ke = s * 16 + koff;
            bf16x8 av0 = ld8(aR0 + ke), av1 = ld8(aR1 + ke);
            bf16x8 bv = ld8(bR + ke);
            c0 = __builtin_amdgcn_mfma_f32_32x32x16_bf16(av0, bv, c0, 0, 0, 0);
            c1 = __builtin_amdgcn_mfma_f32_32x32x16_bf16(av1, bv, c1, 0, 0, 0);
        }
    }
    {
        const int col = wc * 32 + l31;
#define STORE_X(CC, SUB)                                                       \
        {                                                                      \
            _Pragma("unroll")                                                  \
            for (int r = 0; r < 16; ++r) {                                     \
                int row = wr * 64 + (SUB) * 32 + CROW(r, lhi);                 \
                int gn = n0 + row;                                             \
                if (gn < n) {                                                  \
                    float v = fmaxf(CC[r], 0.f);                               \
                    x[(size_t)gn * EMB + col] = v;                             \
                    xb[(size_t)gn * EMB + col] = f2bf(v);                      \
                }                                                              \
            }                                                                  \
        }
        STORE_X(c0, 0) STORE_X(c1, 1)
#undef STORE_X
    }
}

// ================= MFMA edge layer (r5 structure, dst packed in eab4.w) ======
// 128 edges/block, 4 waves, 4 blocks/CU. dst-sorted edges; all-atomic 32-row
// seg-reduce (one atomic per run per col). Weights read from global (L2-hot).
__global__ __launch_bounds__(ETHR, 4) void k_edge_mfma(
    const ushort_t* __restrict__ xb,
    const uint4v* __restrict__ eab4,    // sorted: [dn|rxn, ryn|flag, src, dst]
    const ushort_t* __restrict__ w1t,   // [128][148] bf16
    const float* __restrict__ b1,
    const ushort_t* __restrict__ w2t,   // [64][140] bf16
    const float* __restrict__ b2,
    float* __restrict__ aggr, int ne)
{
    __shared__ __align__(16) ushort_t s_A[TE * K1PAD];   // 37888 B; H / M overlay
    __shared__ int s_dst[TE];
    ushort_t* s_H = s_A;                                 // [128][140] bf16 phase 2
    float*    s_M = reinterpret_cast<float*>(s_A);       // [128][68] fp32 phase 3

    const int tid  = threadIdx.x;
    const int lane = tid & 63, wid = tid >> 6;
    const int wr = wid >> 1, wc = wid & 1;
    const int l31 = lane & 31, lhi = lane >> 5;
    const int e0 = blockIdx.x * TE;

    // ---- gather: [x[dst] | x[src] | feat | 0pad] per edge row ----
    // (ne % TE == 0, so no bounds checks)
    {
        const int e = tid >> 1, h = tid & 1, ge = e0 + e;
        ushort_t* arow = s_A + e * K1PAD;                // 296B stride, 8B-aligned
        uint4v ev = eab4[ge];
        if (h == 0) {
            s_dst[e] = (int)ev.w;
            const uint2* sp = reinterpret_cast<const uint2*>(xb + (size_t)ev.w * EMB);
            uint2* dp = reinterpret_cast<uint2*>(arow);
#pragma unroll
            for (int i = 0; i < 16; ++i) dp[i] = sp[i];
        } else {
            const uint2* sp = reinterpret_cast<const uint2*>(xb + (size_t)ev.z * EMB);
            uint2* dp = reinterpret_cast<uint2*>(arow + EMB);
#pragma unroll
            for (int i = 0; i < 16; ++i) dp[i] = sp[i];
            // features: [dn, rxn, ryn, cos, sin, dn2, 0, 0]
            uint_t dn_b = ev.x & 0xFFFFu, rxn_b = ev.x >> 16;
            uint_t ryn_b = ev.y & 0xFFFFu, flag = ev.y >> 16;
            uint_t cos_b = flag ? 0x3F80u : rxn_b;       // dist==0 -> cos=1,sin=0
            uint_t sin_b = flag ? 0u : ryn_b;
            union { uint_t u; float f; } cv; cv.u = dn_b << 16;
            uint_t dn2_b = (uint_t)f2bf(cv.f * cv.f);
            uint2* ap = reinterpret_cast<uint2*>(arow + 2 * EMB);
            ap[0] = make_uint2(dn_b | (rxn_b << 16), ryn_b | (cos_b << 16));
            ap[1] = make_uint2(sin_b | (dn2_b << 16), 0u);
            uint2* pp = reinterpret_cast<uint2*>(arow + CAT);   // k 136..147
            pp[0] = make_uint2(0u, 0u); pp[1] = make_uint2(0u, 0u);
            pp[2] = make_uint2(0u, 0u);
        }
    }
    __syncthreads();

    // ---- GEMM1: [128 x 144] @ [144 x 128]; B from global (L2-hot) ----
    f32x16 a00, a01, a10, a11;
    {
        float bv0 = b1[wc * 64 + l31], bv1 = b1[wc * 64 + 32 + l31];
#pragma unroll
        for (int i = 0; i < 16; ++i) { a00[i] = bv0; a01[i] = bv1; a10[i] = bv0; a11[i] = bv1; }
    }
    {
        const ushort_t* aR0 = s_A + (wr * 64 + l31) * K1PAD;
        const ushort_t* aR1 = aR0 + 32 * K1PAD;
        const ushort_t* bR0 = w1t + (wc * 64 + l31) * K1PAD;
        const ushort_t* bR1 = bR0 + 32 * K1PAD;
        const int koff = lhi * 8;
#pragma unroll
        for (int s = 0; s < K1STEPS; ++s) {
            const int ke = s * 16 + koff;
            bf16x8 av0 = ld8(aR0 + ke);
            bf16x8 av1 = ld8(aR1 + ke);
            bf16x8 bv0 = ld8(bR0 + ke);
            bf16x8 bv1 = ld8(bR1 + ke);
            a00 = __builtin_amdgcn_mfma_f32_32x32x16_bf16(av0, bv0, a00, 0, 0, 0);
            a01 = __builtin_amdgcn_mfma_f32_32x32x16_bf16(av0, bv1, a01, 0, 0, 0);
            a10 = __builtin_amdgcn_mfma_f32_32x32x16_bf16(av1, bv0, a10, 0, 0, 0);
            a11 = __builtin_amdgcn_mfma_f32_32x32x16_bf16(av1, bv1, a11, 0, 0, 0);
        }
    }
    __syncthreads();

    // ---- relu -> bf16 H (overlay) ----
#define WRITE_H(ACC, SUB, NC)                                                  \
    {                                                                          \
        const int col = wc * 64 + (NC) * 32 + l31;                             \
        _Pragma("unroll")                                                      \
        for (int r = 0; r < 16; ++r) {                                         \
            int row = wr * 64 + (SUB) * 32 + CROW(r, lhi);                     \
            s_H[row * K2PAD + col] = f2bf(fmaxf(ACC[r], 0.f));                 \
        }                                                                      \
    }
    WRITE_H(a00, 0, 0) WRITE_H(a01, 0, 1) WRITE_H(a10, 1, 0) WRITE_H(a11, 1, 1)
#undef WRITE_H
    __syncthreads();

    // ---- GEMM2: [128 x 128] @ [128 x 64]; B from global ----
    f32x16 c0, c1;
    {
        float bv = b2[wc * 32 + l31];
#pragma unroll
        for (int i = 0; i < 16; ++i) { c0[i] = bv; c1[i] = bv; }
    }
    {
        const ushort_t* aR0 = s_H + (wr * 64 + l31) * K2PAD;
        const ushort_t* aR1 = aR0 + 32 * K2PAD;
        const ushort_t* bR = w2t + (wc * 32 + l31) * K2PAD;
        const int koff = lhi * 8;
#pragma unroll
        for (int s = 0; s < K2STEPS; ++s) {
            const int ke = s * 16 + koff;
            bf16x8 av0 = ld8(aR0 + ke);
            bf16x8 av1 = ld8(aR1 + ke);
            bf16x8 bv = ld8(bR + ke);
            c0 = __builtin_amdgcn_mfma_f32_32x32x16_bf16(av0, bv, c0, 0, 0, 0);
            c1 = __builtin_amdgcn_mfma_f32_32x32x16_bf16(av1, bv, c1, 0, 0, 0);
        }
    }
    __syncthreads();   // H reads done before M overlay

    // ---- messages (x0.25 attention constant) -> fp32 LDS [128][68] ----
    {
        const int col = wc * 32 + l31;
#pragma unroll
        for (int r = 0; r < 16; ++r) {
            int row = wr * 64 + CROW(r, lhi);
            s_M[row * 68 + col] = c0[r] * 0.25f;
            s_M[(row + 32) * 68 + col] = c1[r] * 0.25f;
        }
    }
    __syncthreads();

    // ---- segmented reduction over sorted dst: one atomic per (run, col) ----
    {
        const int col = tid & 63, g = tid >> 6, base = g * 32;
        int cur = s_dst[base];
        float acc = 0.f;
#pragma unroll 8
        for (int r = 0; r < 32; ++r) {
            int d = s_dst[base + r];
            float v = s_M[(base + r) * 68 + col];
            if (d != cur) {                       // wave-uniform
                atomicAdd(aggr + (size_t)cur * EMB + col, acc);
                acc = 0.f; cur = d;
            }
            acc += v;
        }
        atomicAdd(aggr + (size_t)cur * EMB + col, acc);
    }
}

// ================= MFMA node update (zeroes aggr after reading it) ==========
__global__ __launch_bounds__(256, 2) void k_update_mfma(
    float* __restrict__ x, ushort_t* __restrict__ xb,
    float* __restrict__ aggr,
    const float* __restrict__ w1, const float* __restrict__ b1,
    const float* __restrict__ w2, const float* __restrict__ b2,
    const float* __restrict__ g, const float* __restrict__ bb, int n)
{
    __shared__ __align__(16) ushort_t s_A[TB * K2PAD];
    __shared__ __align__(16) ushort_t s_B[TB * K2PAD];
    ushort_t* s_H  = s_A;
    ushort_t* s_W2 = s_B;
    float*    s_U  = reinterpret_cast<float*>(s_B);

    const int tid = threadIdx.x;
    const int lane = tid & 63, wid = tid >> 6;
    const int wr = wid >> 1, wc = wid & 1;
    const int l31 = lane & 31, lhi = lane >> 5;
    const int n0 = blockIdx.x * TB;

    {
        const int row = tid >> 1, h = tid & 1;
        const int gn = n0 + row;
        ushort_t* arow = s_A + row * K2PAD;
        if (h == 0) {
            uint2* dp = reinterpret_cast<uint2*>(arow);
            if (gn < n) {
                const uint2* sp = reinterpret_cast<const uint2*>(xb + (size_t)gn * EMB);
#pragma unroll
                for (int i = 0; i < 16; ++i) dp[i] = sp[i];
            } else {
                const uint2 z = make_uint2(0u, 0u);
#pragma unroll
                for (int i = 0; i < 16; ++i) dp[i] = z;
            }
        } else {
            if (gn < n) {
                float4* sp = reinterpret_cast<float4*>(aggr + (size_t)gn * EMB);
                const float4 z4 = make_float4(0.f, 0.f, 0.f, 0.f);
#pragma unroll
                for (int i = 0; i < 16; ++i) {
                    float4 v = sp[i];
                    sp[i] = z4;                  // zero for next layer's atomics
                    ushort_t* qq = arow + EMB + i * 4;
                    qq[0] = f2bf(v.x); qq[1] = f2bf(v.y); qq[2] = f2bf(v.z); qq[3] = f2bf(v.w);
                }
            } else {
#pragma unroll
                for (int i = 0; i < 16; ++i) {
                    ushort_t* qq = arow + EMB + i * 4;
                    qq[0] = 0; qq[1] = 0; qq[2] = 0; qq[3] = 0;
                }
            }
        }
    }
    for (int i = tid; i < 128 * 128; i += 256) {
        int k = i >> 7, c = i & 127;
        s_B[c * K2PAD + k] = f2bf(w1[i]);
    }
    __syncthreads();

    f32x16 a00, a01, a10, a11;
    {
        float bv0 = b1[wc * 64 + l31], bv1 = b1[wc * 64 + 32 + l31];
#pragma unroll
        for (int i = 0; i < 16; ++i) { a00[i] = bv0; a01[i] = bv1; a10[i] = bv0; a11[i] = bv1; }
    }
    {
        const ushort_t* aR0 = s_A + (wr * 64 + l31) * K2PAD;
        const ushort_t* aR1 = aR0 + 32 * K2PAD;
        const ushort_t* bR0 = s_B + (wc * 64 + l31) * K2PAD;
        const ushort_t* bR1 = bR0 + 32 * K2PAD;
        const int koff = lhi * 8;
#pragma unroll
        for (int s = 0; s < K2STEPS; ++s) {
            const int ke = s * 16 + koff;
            bf16x8 av0 = ld8(aR0 + ke), av1 = ld8(aR1 + ke);
            bf16x8 bv0 = ld8(bR0 + ke), bv1 = ld8(bR1 + ke);
            a00 = __builtin_amdgcn_mfma_f32_32x32x16_bf16(av0, bv0, a00, 0, 0, 0);
            a01 = __builtin_amdgcn_mfma_f32_32x32x16_bf16(av0, bv1, a01, 0, 0, 0);
            a10 = __builtin_amdgcn_mfma_f32_32x32x16_bf16(av1, bv0, a10, 0, 0, 0);
            a11 = __builtin_amdgcn_mfma_f32_32x32x16_bf16(av1, bv1, a11, 0, 0, 0);
        }
    }
    __syncthreads();

#define WRITE_H(ACC, SUB, NC)                                                  \
    {                                                                          \
        const int col = wc * 64 + (NC) * 32 + l31;                             \
        _Pragma("unroll")                                                      \
        for (int r = 0; r < 16; ++r) {                                         \
            int row = wr * 64 + (SUB) * 32 + CROW(r, lhi);                     \
            s_H[row * K2PAD + col] = f2bf(fmaxf(ACC[r], 0.f));                 \
        }                                                                      \
    }
    WRITE_H(a00, 0, 0) WRITE_H(a01, 0, 1) WRITE_H(a10, 1, 0) WRITE_H(a11, 1, 1)
#undef WRITE_H
    for (int i = tid; i < HID * EMB; i += 256) {
        int k = i >> 6, c = i & 63;
        s_W2[c * K2PAD + k] = f2bf(w2[i]);
    }
    __syncthreads();

    f32x16 c0, c1;
    {
        float bv = b2[wc * 32 + l31];
#pragma unroll
        for (int i = 0; i < 16; ++i) { c0[i] = bv; c1[i] = bv; }
    }
    {
        const ushort_t* aR0 = s_H + (wr * 64 + l31) * K2PAD;
        const ushort_t* aR1 = aR0 + 32 * K2PAD;
        const ushort_t* bR = s_W2 + (wc * 32 + l31) * K2PAD;
        const int koff = lhi * 8;
#pragma unroll
        for (int s = 0; s < K2STEPS; ++s) {
            const int ke = s * 16 + koff;
            bf16x8 av0 = ld8(aR0 + ke), av1 = ld8(aR1 + ke);
            bf16x8 bv = ld8(bR + ke);
            c0 = __builtin_amdgcn_mfma_f32_32x32x16_bf16(av0, bv, c0, 0, 0, 0);
            c1 = __builtin_amdgcn_mfma_f32_32x32x16_bf16(av1, bv, c1, 0, 0, 0);
        }
    }
    __syncthreads();

    {
        const int col = wc * 32 + l31;
#pragma unroll
        for (int r = 0; r < 16; ++r) {
            int row = wr * 64 + CROW(r, lhi);
            s_U[row * 68 + col] = c0[r];
            s_U[(row + 32) * 68 + col] = c1[r];
        }
    }
    __syncthreads();

    if (tid < TB) {
        int gn = n0 + tid;
        if (gn < n) {
            const float* xr = x + (size_t)gn * EMB;
            float* ur = s_U + tid * 68;
            float sum = 0.f, sum2 = 0.f;
#pragma unroll 8
            for (int q = 0; q < EMB; ++q) {
                float v = xr[q] + ur[q];
                ur[q] = v;
                sum += v; sum2 += v * v;
            }
            float mu = sum * (1.f / EMB);
            float var = fmaxf(sum2 * (1.f / EMB) - mu * mu, 0.f);
            float rs = 1.f / sqrtf(var + 1e-5f);
            float* xo = x + (size_t)gn * EMB;
            ushort_t* xbo = xb + (size_t)gn * EMB;
#pragma unroll 8
            for (int q = 0; q < EMB; ++q) {
                float v = (ur[q] - mu) * rs * g[q] + bb[q];
                xo[q] = v;
                xbo[q] = f2bf(v);
            }
        }
    }
}

// ================= MFMA output projection =================
constexpr int OKP = 68;
__global__ __launch_bounds__(256, 2) void k_output_mfma(
    const ushort_t* __restrict__ xb,
    const float* __restrict__ w1, const float* __restrict__ b1,
    const float* __restrict__ w2, const float* __restrict__ b2,
    float* __restrict__ out, int n)
{
    __shared__ __align__(16) ushort_t s_A[TB * OKP];
    __shared__ __align__(16) ushort_t s_B[HID * OKP];
    __shared__ __align__(16) ushort_t s_H[TB * K2PAD];
    __shared__ __align__(16) ushort_t s_W2[EMB * K2PAD];

    const int tid = threadIdx.x;
    const int lane = tid & 63, wid = tid >> 6;
    const int wr = wid >> 1, wc = wid & 1;
    const int l31 = lane & 31, lhi = lane >> 5;
    const int n0 = blockIdx.x * TB;

    for (int i = tid; i < TB * 16; i += 256) {
        int row = i >> 4, q = i & 15;
        int gn = n0 + row;
        uint2 v = make_uint2(0u, 0u);
        if (gn < n) v = reinterpret_cast<const uint2*>(xb + (size_t)gn * EMB)[q];
        *reinterpret_cast<uint2*>(s_A + row * OKP + q * 4) = v;
    }
    for (int i = tid; i < EMB * HID; i += 256) {
        int k = i >> 7, c = i & 127;
        s_B[c * OKP + k] = f2bf(w1[i]);
    }
    for (int i = tid; i < HID * EMB; i += 256) {
        int k = i >> 6, c = i & 63;
        s_W2[c * K2PAD + k] = f2bf(w2[i]);
    }
    __syncthreads();

    f32x16 a00, a01, a10, a11;
    {
        float bv0 = b1[wc * 64 + l31], bv1 = b1[wc * 64 + 32 + l31];
#pragma unroll
        for (int i = 0; i < 16; ++i) { a00[i] = bv0; a01[i] = bv1; a10[i] = bv0; a11[i] = bv1; }
    }
    {
        const ushort_t* aR0 = s_A + (wr * 64 + l31) * OKP;
        const ushort_t* aR1 = aR0 + 32 * OKP;
        const ushort_t* bR0 = s_B + (wc * 64 + l31) * OKP;
        const ushort_t* bR1 = bR0 + 32 * OKP;
        const int koff = lhi * 8;
#pragma unroll
        for (int s = 0; s < 4; ++s) {
            const int ke = s * 16 + koff;
            bf16x8 av0 = ld8(aR0 + ke), av1 = ld8(aR1 + ke);
            bf16x8 bv0 = ld8(bR0 + ke), bv1 = ld8(bR1 + ke);
            a00 = __builtin_amdgcn_mfma_f32_32x32x16_bf16(av0, bv0, a00, 0, 0, 0);
            a01 = __builtin_amdgcn_mfma_f32_32x32x16_bf16(av0, bv1, a01, 0, 0, 0);
            a10 = __builtin_amdgcn_mfma_f32_32x32x16_bf16(av1, bv0, a10, 0, 0, 0);
            a11 = __builtin_amdgcn_mfma_f32_32x32x16_bf16(av1, bv1, a11, 0, 0, 0);
        }
    }
    __syncthreads();

#define WRITE_H(ACC, SUB, NC)                                                  \
    {                                                                          \
        const int col = wc * 64 + (NC) * 32 + l31;                             \
        _Pragma("unroll")                                                      \
        for (int r = 0; r < 16; ++r) {                                         \
            int row = wr * 64 + (SUB) * 32 + CROW(r, lhi);                     \
            s_H[row * K2PAD + col] = f2bf(fmaxf(ACC[r], 0.f));                 \
        }                                                                      \
    }
    WRITE_H(a00, 0, 0) WRITE_H(a01, 0, 1) WRITE_H(a10, 1, 0) WRITE_H(a11, 1, 1)
#undef WRITE_H
    __syncthreads();

    f32x16 c0, c1;
    {
        float bv = b2[wc * 32 + l31];
#pragma unroll
        for (int i = 0; i < 16; ++i) { c0[i] = bv; c1[i] = bv; }
    }
    {
        const ushort_t* aR0 = s_H + (wr * 64 + l31) * K2PAD;
        const ushort_t* aR1 = aR0 + 32 * K2PAD;
        const ushort_t* bR = s_W2 + (wc * 32 + l31) * K2PAD;
        const int koff = lhi * 8;
#pragma unroll
        for (int s = 0; s < K2STEPS; ++s) {
            const int ke = s * 16 + koff;
            bf16x8 av0 = ld8(aR0 + ke), av1 = ld8(aR1 + ke);
            bf16x8 bv = ld8(bR + ke);
            c0 = __builtin_amdgcn_mfma_f32_32x32x16_bf16(av0, bv, c0, 0, 0, 0);
            c1 = __builtin_amdgcn_mfma_f32_32x32x16_bf16(av1, bv, c1, 0, 0, 0);
        }
    }
    {
        const int col = wc * 32 + l31;
#pragma unroll
        for (int r = 0; r < 16; ++r) {
            int row0 = wr * 64 + CROW(r, lhi);
            int g0 = n0 + row0, g1 = g0 + 32;
            if (g0 < n) out[(size_t)g0 * EMB + col] = c0[r];
            if (g1 < n) out[(size_t)g1 * EMB + col] = c1[r];
        }
    }
}

extern "C" void kernel_launch(void* const* d_in, const int* in_sizes, int n_in,
                              void* d_out, int out_size, void* d_ws, size_t ws_size,
                              hipStream_t stream)
{
    const float* obs     = (const float*)d_in[0];
    const float* pos     = (const float*)d_in[1];
    const int*   eidx    = (const int*)d_in[2];
    const float* enc_w1  = (const float*)d_in[3];
    const float* enc_b1  = (const float*)d_in[4];
    const float* enc_lng = (const float*)d_in[5];
    const float* enc_lnb = (const float*)d_in[6];
    const float* enc_w2  = (const float*)d_in[7];
    const float* enc_b2  = (const float*)d_in[8];
    const float* msg_w1  = (const float*)d_in[9];
    const float* msg_b1  = (const float*)d_in[10];
    const float* msg_w2  = (const float*)d_in[11];
    const float* msg_b2  = (const float*)d_in[12];
    // d_in[13..16] = att_* : mathematically unused (mean(softmax) == 0.25)
    const float* upd_w1  = (const float*)d_in[17];
    const float* upd_b1  = (const float*)d_in[18];
    const float* upd_w2  = (const float*)d_in[19];
    const float* upd_b2  = (const float*)d_in[20];
    const float* ln_g    = (const float*)d_in[21];
    const float* ln_b    = (const float*)d_in[22];
    const float* out_w1  = (const float*)d_in[23];
    const float* out_b1  = (const float*)d_in[24];
    const float* out_w2  = (const float*)d_in[25];
    const float* out_b2  = (const float*)d_in[26];

    const int n  = in_sizes[0] / OBS;   // 50000
    const int ne = in_sizes[2] / 2;     // 800000
    const int* src = eidx;
    const int* dst = eidx + ne;

    char* ws = (char*)d_ws;
    float*    x     = (float*)ws;                          // 12,800,000 B
    ushort_t* xbuf  = (ushort_t*)(ws + 12800000);          //  6,400,000 B
    uint4v*   eab4  = (uint4v*)(ws + 19200000);            // 12,800,000 B (sorted)
    float*    aggr  = (float*)(ws + 32000000);             // 12,800,000 B
    ushort_t* w1t   = (ushort_t*)(ws + 44800000);          //    113,664 B
    ushort_t* w2t   = (ushort_t*)(ws + 44913664);          //     53,760 B
    int*      hist  = (int*)(ws + 44967424);               //    200,000 B
    int*      scan  = (int*)(ws + 45167424);               //    200,000 B
    int*      bsum  = (int*)(ws + 45367424);               //        512 B
    // total ~45.4 MB (< 51.2 MB proven safe)

    const int NB1 = (NN + 511) / 512;   // 98
    const int nb  = (n + TB - 1) / TB;  // 391

    // ---- counting sort of edges by dst (+ fused edge features) ----
    hipMemsetAsync(hist, 0, NN * sizeof(int), stream);
    k_hist<<<(ne + 255) / 256, 256, 0, stream>>>(dst, hist, ne);
    k_scan1<<<NB1, 512, 0, stream>>>(hist, scan, bsum, NN);
    k_scan3<<<NB1, 512, 0, stream>>>(scan, bsum, NN);
    k_scatter_feat<<<(ne + 255) / 256, 256, 0, stream>>>(pos, src, dst, scan,
                                                         eab4, ne);

    k_prep<<<(3 * HID * K1PAD + 255) / 256, 256, 0, stream>>>(msg_w1, msg_w2, w1t, w2t);
    k_encoder_mfma<<<nb, 256, 0, stream>>>(obs, enc_w1, enc_b1, enc_lng, enc_lnb,
                                           enc_w2, enc_b2, x, xbuf, n);
    // aggr zeroed once here; k_update re-zeroes it for the next layer.
    hipMemsetAsync(aggr, 0, (size_t)n * EMB * sizeof(float), stream);

    for (int l = 0; l < 3; ++l) {
        k_edge_mfma<<<ne / TE, ETHR, 0, stream>>>(
            xbuf, eab4,
            w1t + (size_t)l * HID * K1PAD, msg_b1 + (size_t)l * HID,
            w2t + (size_t)l * EMB * K2PAD, msg_b2 + (size_t)l * EMB,
            aggr, ne);
        k_update_mfma<<<nb, 256, 0, stream>>>(
            x, xbuf, aggr,
            upd_w1 + (size_t)l * 2 * EMB * HID, upd_b1 + (size_t)l * HID,
            upd_w2 + (size_t)l * HID * EMB, upd_b2 + (size_t)l * EMB,
            ln_g + (size_t)l * EMB, ln_b + (size_t)l * EMB, n);
    }
    k_output_mfma<<<nb, 256, 0, stream>>>(
        xbuf, out_w1, out_b1, out_w2, out_b2, (float*)d_out, n);
}

// Round 10
// 713.756 us; speedup vs baseline: 2.4641x; 1.0577x over previous
//
#include <hip/hip_runtime.h>
#include <hip/hip_bf16.h>

typedef unsigned short ushort_t;
typedef unsigned int uint_t;

constexpr int OBS  = 25;
constexpr int HID  = 128;
constexpr int EMB  = 64;
constexpr int CAT  = 136;   // 2*EMB + EDGE_DIM
constexpr int NN   = 50000;

// MFMA edge-kernel geometry: TE=128 rows, 8 waves, LDS 38.4KB -> 4 blk/CU,
// 32 waves/CU (vs r9's 16) for memory-latency overlap.
constexpr int TE      = 128;          // edges per block (800000 % 128 == 0)
constexpr int ETHR    = 512;          // 8 waves
constexpr int K1PAD   = 148;          // cat K padded (136 -> 144 used, 148 stride)
constexpr int K2PAD   = 140;          // hid K stride (128 used)
constexpr int K1STEPS = 9;            // 9*16 = 144
constexpr int K2STEPS = 8;            // 8*16 = 128

// node-kernel geometry
constexpr int TB = 128;

typedef __attribute__((ext_vector_type(8)))  short bf16x8;
typedef __attribute__((ext_vector_type(16))) float f32x16;
typedef __attribute__((ext_vector_type(4)))  uint_t uint4v;

__device__ __forceinline__ ushort_t f2bf(float f) {
    union { float f; uint_t u; } v; v.f = f;
    uint_t r = v.u + 0x7FFFu + ((v.u >> 16) & 1u);   // RNE
    return (ushort_t)(r >> 16);
}

__device__ __forceinline__ bf16x8 ld8(const ushort_t* p) {
    uint2 lo = *reinterpret_cast<const uint2*>(p);
    uint2 hi = *reinterpret_cast<const uint2*>(p + 4);
    uint4 u = make_uint4(lo.x, lo.y, hi.x, hi.y);
    return __builtin_bit_cast(bf16x8, u);
}

// C-fragment row map for 32x32x16 (HW-verified): col = l31 within 32-col tile,
// row = 4*lhi + (r&3) + 8*(r>>2) within the 32-row sub-tile.
#define CROW(R, LHI) (4 * (LHI) + ((R) & 3) + 8 * ((R) >> 2))

// ================= counting sort of edges by dst =================
__global__ __launch_bounds__(256) void k_hist(
    const int* __restrict__ dst, int* __restrict__ hist, int ne)
{
    int e = blockIdx.x * 256 + threadIdx.x;
    if (e < ne) atomicAdd(&hist[dst[e]], 1);
}

__global__ __launch_bounds__(512) void k_scan1(
    const int* __restrict__ hist, int* __restrict__ scanned,
    int* __restrict__ bsum, int nk)
{
    __shared__ int s[512];
    int t = threadIdx.x, i = blockIdx.x * 512 + t;
    int v = (i < nk) ? hist[i] : 0;
    s[t] = v; __syncthreads();
#pragma unroll
    for (int off = 1; off < 512; off <<= 1) {
        int x = (t >= off) ? s[t - off] : 0;
        __syncthreads();
        s[t] += x;
        __syncthreads();
    }
    if (i < nk) scanned[i] = s[t] - v;          // exclusive within block
    if (t == 511) bsum[blockIdx.x] = s[511];
}

// merged scan2+scan3: each block computes its bsum prefix locally
__global__ __launch_bounds__(512) void k_scan3(
    int* __restrict__ scanned, const int* __restrict__ bsum, int nk)
{
    __shared__ int pref;
    if (threadIdx.x == 0) {
        int run = 0;
        for (int b = 0; b < (int)blockIdx.x; ++b) run += bsum[b];
        pref = run;
    }
    __syncthreads();
    int i = blockIdx.x * 512 + threadIdx.x;
    if (i < nk) scanned[i] += pref;
}

// scatter edges into dst-sorted order; 16B/edge: [dn|rxn, ryn|selfflag, src, dst]
__global__ __launch_bounds__(256) void k_scatter_feat(
    const float* __restrict__ pos, const int* __restrict__ src,
    const int* __restrict__ dst, int* __restrict__ ofs,
    uint4v* __restrict__ eab4, int ne)
{
    int e = blockIdx.x * 256 + threadIdx.x;
    if (e >= ne) return;
    int s = src[e], d = dst[e];
    float rx = pos[d * 2 + 0] - pos[s * 2 + 0];
    float ry = pos[d * 2 + 1] - pos[s * 2 + 1];
    float dist = sqrtf(rx * rx + ry * ry);
    float inv = 1.f / (dist + 1e-6f);
    float dn = dist * (1.f / 1500.f);
    uint_t ux = (uint_t)f2bf(dn) | ((uint_t)f2bf(rx * inv) << 16);
    uint_t uy = (uint_t)f2bf(ry * inv) | ((dist > 0.f ? 0u : 1u) << 16);
    int p = atomicAdd(&ofs[d], 1);
    uint4v ev = { ux, uy, (uint_t)s, (uint_t)d };
    eab4[p] = ev;
}

// ================= weight prep: bf16 transposed W1T/W2T =================
__global__ __launch_bounds__(256) void k_prep(
    const float* __restrict__ w1, const float* __restrict__ w2,
    ushort_t* __restrict__ w1t, ushort_t* __restrict__ w2t)
{
    int t = blockIdx.x * 256 + threadIdx.x;
    const int n1 = 3 * HID * K1PAD;          // [l][c][k]
    if (t < n1) {
        int l = t / (HID * K1PAD), rem = t % (HID * K1PAD);
        int c = rem / K1PAD, k = rem % K1PAD;
        float v = (k < CAT) ? w1[(size_t)l * CAT * HID + (size_t)k * HID + c] : 0.f;
        w1t[t] = f2bf(v);
    }
    const int n2 = 3 * EMB * K2PAD;          // [l][c][k]
    if (t < n2) {
        int l = t / (EMB * K2PAD), rem = t % (EMB * K2PAD);
        int c = rem / K2PAD, k = rem % K2PAD;
        float v = (k < HID) ? w2[(size_t)l * HID * EMB + (size_t)k * EMB + c] : 0.f;
        w2t[t] = f2bf(v);
    }
}

// ================= MFMA encoder =================
constexpr int EKP = 36;
__global__ __launch_bounds__(256, 1) void k_encoder_mfma(
    const float* __restrict__ obs,
    const float* __restrict__ w1, const float* __restrict__ b1,
    const float* __restrict__ lng, const float* __restrict__ lnb,
    const float* __restrict__ w2, const float* __restrict__ b2,
    float* __restrict__ x, ushort_t* __restrict__ xb, int n)
{
    __shared__ __align__(16) ushort_t s_OB[TB * EKP];
    __shared__ __align__(16) ushort_t s_B1[HID * EKP];
    __shared__ __align__(16) float    s_G[TB * 132];
    __shared__ __align__(16) ushort_t s_H[TB * K2PAD];
    __shared__ __align__(16) ushort_t s_W2[EMB * K2PAD];

    const int tid = threadIdx.x;
    const int lane = tid & 63, wid = tid >> 6;
    const int wr = wid >> 1, wc = wid & 1;
    const int l31 = lane & 31, lhi = lane >> 5;
    const int n0 = blockIdx.x * TB;

    for (int i = tid; i < TB * 32; i += 256) {
        int row = i >> 5, k = i & 31;
        int gn = n0 + row;
        float v = (gn < n && k < OBS) ? obs[(size_t)gn * OBS + k] : 0.f;
        s_OB[row * EKP + k] = f2bf(v);
    }
    for (int i = tid; i < 32 * HID; i += 256) {
        int k = i >> 7, c = i & 127;
        float v = (k < OBS) ? w1[k * HID + c] : 0.f;
        s_B1[c * EKP + k] = f2bf(v);
    }
    __syncthreads();

    f32x16 a00, a01, a10, a11;
    {
        float bv0 = b1[wc * 64 + l31], bv1 = b1[wc * 64 + 32 + l31];
#pragma unroll
        for (int i = 0; i < 16; ++i) { a00[i] = bv0; a01[i] = bv1; a10[i] = bv0; a11[i] = bv1; }
    }
    {
        const ushort_t* aR0 = s_OB + (wr * 64 + l31) * EKP;
        const ushort_t* aR1 = aR0 + 32 * EKP;
        const ushort_t* bR0 = s_B1 + (wc * 64 + l31) * EKP;
        const ushort_t* bR1 = bR0 + 32 * EKP;
        const int koff = lhi * 8;
#pragma unroll
        for (int s = 0; s < 2; ++s) {
            const int ke = s * 16 + koff;
            bf16x8 av0 = ld8(aR0 + ke), av1 = ld8(aR1 + ke);
            bf16x8 bv0 = ld8(bR0 + ke), bv1 = ld8(bR1 + ke);
            a00 = __builtin_amdgcn_mfma_f32_32x32x16_bf16(av0, bv0, a00, 0, 0, 0);
            a01 = __builtin_amdgcn_mfma_f32_32x32x16_bf16(av0, bv1, a01, 0, 0, 0);
            a10 = __builtin_amdgcn_mfma_f32_32x32x16_bf16(av1, bv0, a10, 0, 0, 0);
            a11 = __builtin_amdgcn_mfma_f32_32x32x16_bf16(av1, bv1, a11, 0, 0, 0);
        }
    }
#define WRITE_G(ACC, SUB, NC)                                                  \
    {                                                                          \
        const int col = wc * 64 + (NC) * 32 + l31;                             \
        _Pragma("unroll")                                                      \
        for (int r = 0; r < 16; ++r) {                                         \
            int row = wr * 64 + (SUB) * 32 + CROW(r, lhi);                     \
            s_G[row * 132 + col] = ACC[r];                                     \
        }                                                                      \
    }
    WRITE_G(a00, 0, 0) WRITE_G(a01, 0, 1) WRITE_G(a10, 1, 0) WRITE_G(a11, 1, 1)
#undef WRITE_G
    __syncthreads();

    for (int i = tid; i < HID * EMB; i += 256) {
        int k = i >> 6, c = i & 63;
        s_W2[c * K2PAD + k] = f2bf(w2[i]);
    }
    if (tid < TB) {
        float sum = 0.f, sum2 = 0.f;
        const float* gr = s_G + tid * 132;
#pragma unroll 8
        for (int q = 0; q < HID; ++q) { float v = gr[q]; sum += v; sum2 += v * v; }
        float mu = sum * (1.f / HID);
        float var = fmaxf(sum2 * (1.f / HID) - mu * mu, 0.f);
        float rs = 1.f / sqrtf(var + 1e-5f);
        ushort_t* hr = s_H + tid * K2PAD;
#pragma unroll 8
        for (int q = 0; q < HID; ++q) {
            float v = (gr[q] - mu) * rs * lng[q] + lnb[q];
            hr[q] = f2bf(fmaxf(v, 0.f));
        }
    }
    __syncthreads();

    f32x16 c0, c1;
    {
        float bv = b2[wc * 32 + l31];
#pragma unroll
        for (int i = 0; i < 16; ++i) { c0[i] = bv; c1[i] = bv; }
    }
    {
        const ushort_t* aR0 = s_H + (wr * 64 + l31) * K2PAD;
        const ushort_t* aR1 = aR0 + 32 * K2PAD;
        const ushort_t* bR = s_W2 + (wc * 32 + l31) * K2PAD;
        const int koff = lhi * 8;
#pragma unroll
        for (int s = 0; s < K2STEPS; ++s) {
            const int ke = s * 16 + koff;
            bf16x8 av0 = ld8(aR0 + ke), av1 = ld8(aR1 + ke);
            bf16x8 bv = ld8(bR + ke);
            c0 = __builtin_amdgcn_mfma_f32_32x32x16_bf16(av0, bv, c0, 0, 0, 0);
            c1 = __builtin_amdgcn_mfma_f32_32x32x16_bf16(av1, bv, c1, 0, 0, 0);
        }
    }
    {
        const int col = wc * 32 + l31;
#define STORE_X(CC, SUB)                                                       \
        {                                                                      \
            _Pragma("unroll")                                                  \
            for (int r = 0; r < 16; ++r) {                                     \
                int row = wr * 64 + (SUB) * 32 + CROW(r, lhi);                 \
                int gn = n0 + row;                                             \
                if (gn < n) {                                                  \
                    float v = fmaxf(CC[r], 0.f);                               \
                    x[(size_t)gn * EMB + col] = v;                             \
                    xb[(size_t)gn * EMB + col] = f2bf(v);                      \
                }                                                              \
            }                                                                  \
        }
        STORE_X(c0, 0) STORE_X(c1, 1)
#undef STORE_X
    }
}

// ================= MFMA edge layer (r9 structure, 8 waves / 32 waves per CU) =
// 128 edges/block, 512 threads, LDS 38.4KB -> 4 blocks/CU = 32 waves/CU.
// Wave tile: GEMM1 32x64 (2 accs), GEMM2 32x32 (1 acc). Seg-reduce identical
// to r9 (4 x 32-row groups, tid<256, one atomic per run per col).
__global__ __launch_bounds__(ETHR, 8) void k_edge_mfma(
    const ushort_t* __restrict__ xb,
    const uint4v* __restrict__ eab4,    // sorted: [dn|rxn, ryn|flag, src, dst]
    const ushort_t* __restrict__ w1t,   // [128][148] bf16
    const float* __restrict__ b1,
    const ushort_t* __restrict__ w2t,   // [64][140] bf16
    const float* __restrict__ b2,
    float* __restrict__ aggr, int ne)
{
    __shared__ __align__(16) ushort_t s_A[TE * K1PAD];   // 37888 B; H / M overlay
    __shared__ int s_dst[TE];
    ushort_t* s_H = s_A;                                 // [128][140] bf16 phase 2
    float*    s_M = reinterpret_cast<float*>(s_A);       // [128][68] fp32 phase 3

    const int tid  = threadIdx.x;
    const int lane = tid & 63, wid = tid >> 6;
    const int wr = wid >> 1, wc = wid & 1;               // 4 row-grp x 2 col-grp
    const int l31 = lane & 31, lhi = lane >> 5;
    const int e0 = blockIdx.x * TE;

    // ---- gather: 4 threads per edge row: [x[dst] | x[src] | feat | 0pad] ----
    {
        const int e = tid >> 2, h = tid & 3, ge = e0 + e;
        ushort_t* arow = s_A + e * K1PAD;                // 296B stride, 8B-aligned
        uint4v ev = eab4[ge];
        if (h == 0) {
            s_dst[e] = (int)ev.w;
            const uint2* sp = reinterpret_cast<const uint2*>(xb + (size_t)ev.w * EMB);
            uint2* dp = reinterpret_cast<uint2*>(arow);
#pragma unroll
            for (int i = 0; i < 8; ++i) dp[i] = sp[i];
        } else if (h == 1) {
            const uint2* sp = reinterpret_cast<const uint2*>(xb + (size_t)ev.w * EMB) + 8;
            uint2* dp = reinterpret_cast<uint2*>(arow) + 8;
#pragma unroll
            for (int i = 0; i < 8; ++i) dp[i] = sp[i];
        } else if (h == 2) {
            const uint2* sp = reinterpret_cast<const uint2*>(xb + (size_t)ev.z * EMB);
            uint2* dp = reinterpret_cast<uint2*>(arow + EMB);
#pragma unroll
            for (int i = 0; i < 8; ++i) dp[i] = sp[i];
        } else {
            const uint2* sp = reinterpret_cast<const uint2*>(xb + (size_t)ev.z * EMB) + 8;
            uint2* dp = reinterpret_cast<uint2*>(arow + EMB) + 8;
#pragma unroll
            for (int i = 0; i < 8; ++i) dp[i] = sp[i];
            // features: [dn, rxn, ryn, cos, sin, dn2, 0, 0]
            uint_t dn_b = ev.x & 0xFFFFu, rxn_b = ev.x >> 16;
            uint_t ryn_b = ev.y & 0xFFFFu, flag = ev.y >> 16;
            uint_t cos_b = flag ? 0x3F80u : rxn_b;       // dist==0 -> cos=1,sin=0
            uint_t sin_b = flag ? 0u : ryn_b;
            union { uint_t u; float f; } cv; cv.u = dn_b << 16;
            uint_t dn2_b = (uint_t)f2bf(cv.f * cv.f);
            uint2* ap = reinterpret_cast<uint2*>(arow + 2 * EMB);
            ap[0] = make_uint2(dn_b | (rxn_b << 16), ryn_b | (cos_b << 16));
            ap[1] = make_uint2(sin_b | (dn2_b << 16), 0u);
            uint2* pp = reinterpret_cast<uint2*>(arow + CAT);   // k 136..147
            pp[0] = make_uint2(0u, 0u); pp[1] = make_uint2(0u, 0u);
            pp[2] = make_uint2(0u, 0u);
        }
    }
    __syncthreads();

    // ---- GEMM1: [128 x 144] @ [144 x 128]; wave tile 32x64 ----
    f32x16 a0, a1;
    {
        float bv0 = b1[wc * 64 + l31], bv1 = b1[wc * 64 + 32 + l31];
#pragma unroll
        for (int i = 0; i < 16; ++i) { a0[i] = bv0; a1[i] = bv1; }
    }
    {
        const ushort_t* aR = s_A + (wr * 32 + l31) * K1PAD;
        const ushort_t* bR0 = w1t + (wc * 64 + l31) * K1PAD;
        const ushort_t* bR1 = bR0 + 32 * K1PAD;
        const int koff = lhi * 8;
#pragma unroll
        for (int s = 0; s < K1STEPS; ++s) {
            const int ke = s * 16 + koff;
            bf16x8 av = ld8(aR + ke);
            bf16x8 bv0 = ld8(bR0 + ke);
            bf16x8 bv1 = ld8(bR1 + ke);
            a0 = __builtin_amdgcn_mfma_f32_32x32x16_bf16(av, bv0, a0, 0, 0, 0);
            a1 = __builtin_amdgcn_mfma_f32_32x32x16_bf16(av, bv1, a1, 0, 0, 0);
        }
    }
    __syncthreads();

    // ---- relu -> bf16 H (overlay) ----
#define WRITE_H(ACC, NC)                                                       \
    {                                                                          \
        const int col = wc * 64 + (NC) * 32 + l31;                             \
        _Pragma("unroll")                                                      \
        for (int r = 0; r < 16; ++r) {                                         \
            int row = wr * 32 + CROW(r, lhi);                                  \
            s_H[row * K2PAD + col] = f2bf(fmaxf(ACC[r], 0.f));                 \
        }                                                                      \
    }
    WRITE_H(a0, 0) WRITE_H(a1, 1)
#undef WRITE_H
    __syncthreads();

    // ---- GEMM2: [128 x 128] @ [128 x 64]; wave tile 32x32 ----
    f32x16 c0;
    {
        float bv = b2[wc * 32 + l31];
#pragma unroll
        for (int i = 0; i < 16; ++i) c0[i] = bv;
    }
    {
        const ushort_t* aR = s_H + (wr * 32 + l31) * K2PAD;
        const ushort_t* bR = w2t + (wc * 32 + l31) * K2PAD;
        const int koff = lhi * 8;
#pragma unroll
        for (int s = 0; s < K2STEPS; ++s) {
            const int ke = s * 16 + koff;
            bf16x8 av = ld8(aR + ke);
            bf16x8 bv = ld8(bR + ke);
            c0 = __builtin_amdgcn_mfma_f32_32x32x16_bf16(av, bv, c0, 0, 0, 0);
        }
    }
    __syncthreads();   // H reads done before M overlay

    // ---- messages (x0.25 attention constant) -> fp32 LDS [128][68] ----
    {
        const int col = wc * 32 + l31;
#pragma unroll
        for (int r = 0; r < 16; ++r) {
            int row = wr * 32 + CROW(r, lhi);
            s_M[row * 68 + col] = c0[r] * 0.25f;
        }
    }
    __syncthreads();

    // ---- segmented reduction over sorted dst (identical to r9) ----
    if (tid < 256) {
        const int col = tid & 63, g = tid >> 6, base = g * 32;
        int cur = s_dst[base];
        float acc = 0.f;
#pragma unroll 8
        for (int r = 0; r < 32; ++r) {
            int d = s_dst[base + r];
            float v = s_M[(base + r) * 68 + col];
            if (d != cur) {                       // wave-uniform
                atomicAdd(aggr + (size_t)cur * EMB + col, acc);
                acc = 0.f; cur = d;
            }
            acc += v;
        }
        atomicAdd(aggr + (size_t)cur * EMB + col, acc);
    }
}

// ================= MFMA node update (zeroes aggr after reading it) ==========
__global__ __launch_bounds__(256, 2) void k_update_mfma(
    float* __restrict__ x, ushort_t* __restrict__ xb,
    float* __restrict__ aggr,
    const float* __restrict__ w1, const float* __restrict__ b1,
    const float* __restrict__ w2, const float* __restrict__ b2,
    const float* __restrict__ g, const float* __restrict__ bb, int n)
{
    __shared__ __align__(16) ushort_t s_A[TB * K2PAD];
    __shared__ __align__(16) ushort_t s_B[TB * K2PAD];
    ushort_t* s_H  = s_A;
    ushort_t* s_W2 = s_B;
    float*    s_U  = reinterpret_cast<float*>(s_B);

    const int tid = threadIdx.x;
    const int lane = tid & 63, wid = tid >> 6;
    const int wr = wid >> 1, wc = wid & 1;
    const int l31 = lane & 31, lhi = lane >> 5;
    const int n0 = blockIdx.x * TB;

    {
        const int row = tid >> 1, h = tid & 1;
        const int gn = n0 + row;
        ushort_t* arow = s_A + row * K2PAD;
        if (h == 0) {
            uint2* dp = reinterpret_cast<uint2*>(arow);
            if (gn < n) {
                const uint2* sp = reinterpret_cast<const uint2*>(xb + (size_t)gn * EMB);
#pragma unroll
                for (int i = 0; i < 16; ++i) dp[i] = sp[i];
            } else {
                const uint2 z = make_uint2(0u, 0u);
#pragma unroll
                for (int i = 0; i < 16; ++i) dp[i] = z;
            }
        } else {
            if (gn < n) {
                float4* sp = reinterpret_cast<float4*>(aggr + (size_t)gn * EMB);
                const float4 z4 = make_float4(0.f, 0.f, 0.f, 0.f);
#pragma unroll
                for (int i = 0; i < 16; ++i) {
                    float4 v = sp[i];
                    sp[i] = z4;                  // zero for next layer's atomics
                    ushort_t* qq = arow + EMB + i * 4;
                    qq[0] = f2bf(v.x); qq[1] = f2bf(v.y); qq[2] = f2bf(v.z); qq[3] = f2bf(v.w);
                }
            } else {
#pragma unroll
                for (int i = 0; i < 16; ++i) {
                    ushort_t* qq = arow + EMB + i * 4;
                    qq[0] = 0; qq[1] = 0; qq[2] = 0; qq[3] = 0;
                }
            }
        }
    }
    for (int i = tid; i < 128 * 128; i += 256) {
        int k = i >> 7, c = i & 127;
        s_B[c * K2PAD + k] = f2bf(w1[i]);
    }
    __syncthreads();

    f32x16 a00, a01, a10, a11;
    {
        float bv0 = b1[wc * 64 + l31], bv1 = b1[wc * 64 + 32 + l31];
#pragma unroll
        for (int i = 0; i < 16; ++i) { a00[i] = bv0; a01[i] = bv1; a10[i] = bv0; a11[i] = bv1; }
    }
    {
        const ushort_t* aR0 = s_A + (wr * 64 + l31) * K2PAD;
        const ushort_t* aR1 = aR0 + 32 * K2PAD;
        const ushort_t* bR0 = s_B + (wc * 64 + l31) * K2PAD;
        const ushort_t* bR1 = bR0 + 32 * K2PAD;
        const int koff = lhi * 8;
#pragma unroll
        for (int s = 0; s < K2STEPS; ++s) {
            const int ke = s * 16 + koff;
            bf16x8 av0 = ld8(aR0 + ke), av1 = ld8(aR1 + ke);
            bf16x8 bv0 = ld8(bR0 + ke), bv1 = ld8(bR1 + ke);
            a00 = __builtin_amdgcn_mfma_f32_32x32x16_bf16(av0, bv0, a00, 0, 0, 0);
            a01 = __builtin_amdgcn_mfma_f32_32x32x16_bf16(av0, bv1, a01, 0, 0, 0);
            a10 = __builtin_amdgcn_mfma_f32_32x32x16_bf16(av1, bv0, a10, 0, 0, 0);
            a11 = __builtin_amdgcn_mfma_f32_32x32x16_bf16(av1, bv1, a11, 0, 0, 0);
        }
    }
    __syncthreads();

#define WRITE_H(ACC, SUB, NC)                                                  \
    {                                                                          \
        const int col = wc * 64 + (NC) * 32 + l31;                             \
        _Pragma("unroll")                                                      \
        for (int r = 0; r < 16; ++r) {                                         \
            int row = wr * 64 + (SUB) * 32 + CROW(r, lhi);                     \
            s_H[row * K2PAD + col] = f2bf(fmaxf(ACC[r], 0.f));                 \
        }                                                                      \
    }
    WRITE_H(a00, 0, 0) WRITE_H(a01, 0, 1) WRITE_H(a10, 1, 0) WRITE_H(a11, 1, 1)
#undef WRITE_H
    for (int i = tid; i < HID * EMB; i += 256) {
        int k = i >> 6, c = i & 63;
        s_W2[c * K2PAD + k] = f2bf(w2[i]);
    }
    __syncthreads();

    f32x16 c0, c1;
    {
        float bv = b2[wc * 32 + l31];
#pragma unroll
        for (int i = 0; i < 16; ++i) { c0[i] = bv; c1[i] = bv; }
    }
    {
        const ushort_t* aR0 = s_H + (wr * 64 + l31) * K2PAD;
        const ushort_t* aR1 = aR0 + 32 * K2PAD;
        const ushort_t* bR = s_W2 + (wc * 32 + l31) * K2PAD;
        const int koff = lhi * 8;
#pragma unroll
        for (int s = 0; s < K2STEPS; ++s) {
            const int ke = s * 16 + koff;
            bf16x8 av0 = ld8(aR0 + ke), av1 = ld8(aR1 + ke);
            bf16x8 bv = ld8(bR + ke);
            c0 = __builtin_amdgcn_mfma_f32_32x32x16_bf16(av0, bv, c0, 0, 0, 0);
            c1 = __builtin_amdgcn_mfma_f32_32x32x16_bf16(av1, bv, c1, 0, 0, 0);
        }
    }
    __syncthreads();

    {
        const int col = wc * 32 + l31;
#pragma unroll
        for (int r = 0; r < 16; ++r) {
            int row = wr * 64 + CROW(r, lhi);
            s_U[row * 68 + col] = c0[r];
            s_U[(row + 32) * 68 + col] = c1[r];
        }
    }
    __syncthreads();

    if (tid < TB) {
        int gn = n0 + tid;
        if (gn < n) {
            const float* xr = x + (size_t)gn * EMB;
            float* ur = s_U + tid * 68;
            float sum = 0.f, sum2 = 0.f;
#pragma unroll 8
            for (int q = 0; q < EMB; ++q) {
                float v = xr[q] + ur[q];
                ur[q] = v;
                sum += v; sum2 += v * v;
            }
            float mu = sum * (1.f / EMB);
            float var = fmaxf(sum2 * (1.f / EMB) - mu * mu, 0.f);
            float rs = 1.f / sqrtf(var + 1e-5f);
            float* xo = x + (size_t)gn * EMB;
            ushort_t* xbo = xb + (size_t)gn * EMB;
#pragma unroll 8
            for (int q = 0; q < EMB; ++q) {
                float v = (ur[q] - mu) * rs * g[q] + bb[q];
                xo[q] = v;
                xbo[q] = f2bf(v);
            }
        }
    }
}

// ================= MFMA output projection =================
constexpr int OKP = 68;
__global__ __launch_bounds__(256, 2) void k_output_mfma(
    const ushort_t* __restrict__ xb,
    const float* __restrict__ w1, const float* __restrict__ b1,
    const float* __restrict__ w2, const float* __restrict__ b2,
    float* __restrict__ out, int n)
{
    __shared__ __align__(16) ushort_t s_A[TB * OKP];
    __shared__ __align__(16) ushort_t s_B[HID * OKP];
    __shared__ __align__(16) ushort_t s_H[TB * K2PAD];
    __shared__ __align__(16) ushort_t s_W2[EMB * K2PAD];

    const int tid = threadIdx.x;
    const int lane = tid & 63, wid = tid >> 6;
    const int wr = wid >> 1, wc = wid & 1;
    const int l31 = lane & 31, lhi = lane >> 5;
    const int n0 = blockIdx.x * TB;

    for (int i = tid; i < TB * 16; i += 256) {
        int row = i >> 4, q = i & 15;
        int gn = n0 + row;
        uint2 v = make_uint2(0u, 0u);
        if (gn < n) v = reinterpret_cast<const uint2*>(xb + (size_t)gn * EMB)[q];
        *reinterpret_cast<uint2*>(s_A + row * OKP + q * 4) = v;
    }
    for (int i = tid; i < EMB * HID; i += 256) {
        int k = i >> 7, c = i & 127;
        s_B[c * OKP + k] = f2bf(w1[i]);
    }
    for (int i = tid; i < HID * EMB; i += 256) {
        int k = i >> 6, c = i & 63;
        s_W2[c * K2PAD + k] = f2bf(w2[i]);
    }
    __syncthreads();

    f32x16 a00, a01, a10, a11;
    {
        float bv0 = b1[wc * 64 + l31], bv1 = b1[wc * 64 + 32 + l31];
#pragma unroll
        for (int i = 0; i < 16; ++i) { a00[i] = bv0; a01[i] = bv1; a10[i] = bv0; a11[i] = bv1; }
    }
    {
        const ushort_t* aR0 = s_A + (wr * 64 + l31) * OKP;
        const ushort_t* aR1 = aR0 + 32 * OKP;
        const ushort_t* bR0 = s_B + (wc * 64 + l31) * OKP;
        const ushort_t* bR1 = bR0 + 32 * OKP;
        const int koff = lhi * 8;
#pragma unroll
        for (int s = 0; s < 4; ++s) {
            const int ke = s * 16 + koff;
            bf16x8 av0 = ld8(aR0 + ke), av1 = ld8(aR1 + ke);
            bf16x8 bv0 = ld8(bR0 + ke), bv1 = ld8(bR1 + ke);
            a00 = __builtin_amdgcn_mfma_f32_32x32x16_bf16(av0, bv0, a00, 0, 0, 0);
            a01 = __builtin_amdgcn_mfma_f32_32x32x16_bf16(av0, bv1, a01, 0, 0, 0);
            a10 = __builtin_amdgcn_mfma_f32_32x32x16_bf16(av1, bv0, a10, 0, 0, 0);
            a11 = __builtin_amdgcn_mfma_f32_32x32x16_bf16(av1, bv1, a11, 0, 0, 0);
        }
    }
    __syncthreads();

#define WRITE_H(ACC, SUB, NC)                                                  \
    {                                                                          \
        const int col = wc * 64 + (NC) * 32 + l31;                             \
        _Pragma("unroll")                                                      \
        for (int r = 0; r < 16; ++r) {                                         \
            int row = wr * 64 + (SUB) * 32 + CROW(r, lhi);                     \
            s_H[row * K2PAD + col] = f2bf(fmaxf(ACC[r], 0.f));                 \
        }                                                                      \
    }
    WRITE_H(a00, 0, 0) WRITE_H(a01, 0, 1) WRITE_H(a10, 1, 0) WRITE_H(a11, 1, 1)
#undef WRITE_H
    __syncthreads();

    f32x16 c0, c1;
    {
        float bv = b2[wc * 32 + l31];
#pragma unroll
        for (int i = 0; i < 16; ++i) { c0[i] = bv; c1[i] = bv; }
    }
    {
        const ushort_t* aR0 = s_H + (wr * 64 + l31) * K2PAD;
        const ushort_t* aR1 = aR0 + 32 * K2PAD;
        const ushort_t* bR = s_W2 + (wc * 32 + l31) * K2PAD;
        const int koff = lhi * 8;
#pragma unroll
        for (int s = 0; s < K2STEPS; ++s) {
            const int ke = s * 16 + koff;
            bf16x8 av0 = ld8(aR0 + ke), av1 = ld8(aR1 + ke);
            bf16x8 bv = ld8(bR + ke);
            c0 = __builtin_amdgcn_mfma_f32_32x32x16_bf16(av0, bv, c0, 0, 0, 0);
            c1 = __builtin_amdgcn_mfma_f32_32x32x16_bf16(av1, bv, c1, 0, 0, 0);
        }
    }
    {
        const int col = wc * 32 + l31;
#pragma unroll
        for (int r = 0; r < 16; ++r) {
            int row0 = wr * 64 + CROW(r, lhi);
            int g0 = n0 + row0, g1 = g0 + 32;
            if (g0 < n) out[(size_t)g0 * EMB + col] = c0[r];
            if (g1 < n) out[(size_t)g1 * EMB + col] = c1[r];
        }
    }
}

extern "C" void kernel_launch(void* const* d_in, const int* in_sizes, int n_in,
                              void* d_out, int out_size, void* d_ws, size_t ws_size,
                              hipStream_t stream)
{
    const float* obs     = (const float*)d_in[0];
    const float* pos     = (const float*)d_in[1];
    const int*   eidx    = (const int*)d_in[2];
    const float* enc_w1  = (const float*)d_in[3];
    const float* enc_b1  = (const float*)d_in[4];
    const float* enc_lng = (const float*)d_in[5];
    const float* enc_lnb = (const float*)d_in[6];
    const float* enc_w2  = (const float*)d_in[7];
    const float* enc_b2  = (const float*)d_in[8];
    const float* msg_w1  = (const float*)d_in[9];
    const float* msg_b1  = (const float*)d_in[10];
    const float* msg_w2  = (const float*)d_in[11];
    const float* msg_b2  = (const float*)d_in[12];
    // d_in[13..16] = att_* : mathematically unused (mean(softmax) == 0.25)
    const float* upd_w1  = (const float*)d_in[17];
    const float* upd_b1  = (const float*)d_in[18];
    const float* upd_w2  = (const float*)d_in[19];
    const float* upd_b2  = (const float*)d_in[20];
    const float* ln_g    = (const float*)d_in[21];
    const float* ln_b    = (const float*)d_in[22];
    const float* out_w1  = (const float*)d_in[23];
    const float* out_b1  = (const float*)d_in[24];
    const float* out_w2  = (const float*)d_in[25];
    const float* out_b2  = (const float*)d_in[26];

    const int n  = in_sizes[0] / OBS;   // 50000
    const int ne = in_sizes[2] / 2;     // 800000
    const int* src = eidx;
    const int* dst = eidx + ne;

    char* ws = (char*)d_ws;
    float*    x     = (float*)ws;                          // 12,800,000 B
    ushort_t* xbuf  = (ushort_t*)(ws + 12800000);          //  6,400,000 B
    uint4v*   eab4  = (uint4v*)(ws + 19200000);            // 12,800,000 B (sorted)
    float*    aggr  = (float*)(ws + 32000000);             // 12,800,000 B
    ushort_t* w1t   = (ushort_t*)(ws + 44800000);          //    113,664 B
    ushort_t* w2t   = (ushort_t*)(ws + 44913664);          //     53,760 B
    int*      hist  = (int*)(ws + 44967424);               //    200,000 B
    int*      scan  = (int*)(ws + 45167424);               //    200,000 B
    int*      bsum  = (int*)(ws + 45367424);               //        512 B
    // total ~45.4 MB (< 51.2 MB proven safe)

    const int NB1 = (NN + 511) / 512;   // 98
    const int nb  = (n + TB - 1) / TB;  // 391

    // ---- counting sort of edges by dst (+ fused edge features) ----
    hipMemsetAsync(hist, 0, NN * sizeof(int), stream);
    k_hist<<<(ne + 255) / 256, 256, 0, stream>>>(dst, hist, ne);
    k_scan1<<<NB1, 512, 0, stream>>>(hist, scan, bsum, NN);
    k_scan3<<<NB1, 512, 0, stream>>>(scan, bsum, NN);
    k_scatter_feat<<<(ne + 255) / 256, 256, 0, stream>>>(pos, src, dst, scan,
                                                         eab4, ne);

    k_prep<<<(3 * HID * K1PAD + 255) / 256, 256, 0, stream>>>(msg_w1, msg_w2, w1t, w2t);
    k_encoder_mfma<<<nb, 256, 0, stream>>>(obs, enc_w1, enc_b1, enc_lng, enc_lnb,
                                           enc_w2, enc_b2, x, xbuf, n);
    // aggr zeroed once here; k_update re-zeroes it for the next layer.
    hipMemsetAsync(aggr, 0, (size_t)n * EMB * sizeof(float), stream);

    for (int l = 0; l < 3; ++l) {
        k_edge_mfma<<<ne / TE, ETHR, 0, stream>>>(
            xbuf, eab4,
            w1t + (size_t)l * HID * K1PAD, msg_b1 + (size_t)l * HID,
            w2t + (size_t)l * EMB * K2PAD, msg_b2 + (size_t)l * EMB,
            aggr, ne);
        k_update_mfma<<<nb, 256, 0, stream>>>(
            x, xbuf, aggr,
            upd_w1 + (size_t)l * 2 * EMB * HID, upd_b1 + (size_t)l * HID,
            upd_w2 + (size_t)l * HID * EMB, upd_b2 + (size_t)l * EMB,
            ln_g + (size_t)l * EMB, ln_b + (size_t)l * EMB, n);
    }
    k_output_mfma<<<nb, 256, 0, stream>>>(
        xbuf, out_w1, out_b1, out_w2, out_b2, (float*)d_out, n);
}

// Round 11
// 678.290 us; speedup vs baseline: 2.5929x; 1.0523x over previous
//
#include <hip/hip_runtime.h>
#include <hip/hip_bf16.h>

typedef unsigned short ushort_t;
typedef unsigned int uint_t;

constexpr int OBS  = 25;
constexpr int HID  = 128;
constexpr int EMB  = 64;
constexpr int CAT  = 136;   // 2*EMB + EDGE_DIM
constexpr int NN   = 50000;

// MFMA edge-kernel geometry (r10 banked: 140us, 0 conflicts, 76% occupancy)
constexpr int TE      = 128;          // edges per block (800000 % 128 == 0)
constexpr int ETHR    = 512;          // 8 waves
constexpr int K1PAD   = 148;          // cat K padded (136 -> 144 used)
constexpr int K2PAD   = 140;          // hid K stride (128 used)
constexpr int K1STEPS = 9;            // 9*16 = 144
constexpr int K2STEPS = 8;            // 8*16 = 128

// node-kernel geometry: 64 rows/block, 256 threads (4 waves)
constexpr int TBN = 64;
constexpr int EKP = 36;               // obs K stride (25 -> 32 used)
constexpr int XKP = 68;               // x/EMB K stride (64 used)

typedef __attribute__((ext_vector_type(8)))  short bf16x8;
typedef __attribute__((ext_vector_type(16))) float f32x16;
typedef __attribute__((ext_vector_type(4)))  uint_t uint4v;

__device__ __forceinline__ ushort_t f2bf(float f) {
    union { float f; uint_t u; } v; v.f = f;
    uint_t r = v.u + 0x7FFFu + ((v.u >> 16) & 1u);   // RNE
    return (ushort_t)(r >> 16);
}

__device__ __forceinline__ bf16x8 ld8(const ushort_t* p) {
    uint2 lo = *reinterpret_cast<const uint2*>(p);
    uint2 hi = *reinterpret_cast<const uint2*>(p + 4);
    uint4 u = make_uint4(lo.x, lo.y, hi.x, hi.y);
    return __builtin_bit_cast(bf16x8, u);
}

// C-fragment row map for 32x32x16 (HW-verified): col = l31 within 32-col tile,
// row = 4*lhi + (r&3) + 8*(r>>2) within the 32-row sub-tile.
#define CROW(R, LHI) (4 * (LHI) + ((R) & 3) + 8 * ((R) >> 2))

// ================= counting sort of edges by dst =================
__global__ __launch_bounds__(256) void k_hist(
    const int* __restrict__ dst, int* __restrict__ hist, int ne)
{
    int e = blockIdx.x * 256 + threadIdx.x;
    if (e < ne) atomicAdd(&hist[dst[e]], 1);
}

__global__ __launch_bounds__(512) void k_scan1(
    const int* __restrict__ hist, int* __restrict__ scanned,
    int* __restrict__ bsum, int nk)
{
    __shared__ int s[512];
    int t = threadIdx.x, i = blockIdx.x * 512 + t;
    int v = (i < nk) ? hist[i] : 0;
    s[t] = v; __syncthreads();
#pragma unroll
    for (int off = 1; off < 512; off <<= 1) {
        int x = (t >= off) ? s[t - off] : 0;
        __syncthreads();
        s[t] += x;
        __syncthreads();
    }
    if (i < nk) scanned[i] = s[t] - v;
    if (t == 511) bsum[blockIdx.x] = s[511];
}

__global__ __launch_bounds__(512) void k_scan3(
    int* __restrict__ scanned, const int* __restrict__ bsum, int nk)
{
    __shared__ int pref;
    if (threadIdx.x == 0) {
        int run = 0;
        for (int b = 0; b < (int)blockIdx.x; ++b) run += bsum[b];
        pref = run;
    }
    __syncthreads();
    int i = blockIdx.x * 512 + threadIdx.x;
    if (i < nk) scanned[i] += pref;
}

// scatter edges into dst-sorted order; 16B/edge: [dn|rxn, ryn|selfflag, src, dst]
__global__ __launch_bounds__(256) void k_scatter_feat(
    const float* __restrict__ pos, const int* __restrict__ src,
    const int* __restrict__ dst, int* __restrict__ ofs,
    uint4v* __restrict__ eab4, int ne)
{
    int e = blockIdx.x * 256 + threadIdx.x;
    if (e >= ne) return;
    int s = src[e], d = dst[e];
    float rx = pos[d * 2 + 0] - pos[s * 2 + 0];
    float ry = pos[d * 2 + 1] - pos[s * 2 + 1];
    float dist = sqrtf(rx * rx + ry * ry);
    float inv = 1.f / (dist + 1e-6f);
    float dn = dist * (1.f / 1500.f);
    uint_t ux = (uint_t)f2bf(dn) | ((uint_t)f2bf(rx * inv) << 16);
    uint_t uy = (uint_t)f2bf(ry * inv) | ((dist > 0.f ? 0u : 1u) << 16);
    int p = atomicAdd(&ofs[d], 1);
    uint4v ev = { ux, uy, (uint_t)s, (uint_t)d };
    eab4[p] = ev;
}

// ================= weight prep: ALL weights -> transposed bf16 ==============
__global__ __launch_bounds__(256) void k_prep_all(
    const float* __restrict__ msg_w1, const float* __restrict__ msg_w2,
    const float* __restrict__ upd_w1, const float* __restrict__ upd_w2,
    const float* __restrict__ enc_w1, const float* __restrict__ enc_w2,
    const float* __restrict__ out_w1, const float* __restrict__ out_w2,
    ushort_t* __restrict__ mw1t, ushort_t* __restrict__ mw2t,
    ushort_t* __restrict__ uw1t, ushort_t* __restrict__ uw2t,
    ushort_t* __restrict__ ew1t, ushort_t* __restrict__ ew2t,
    ushort_t* __restrict__ ow1t, ushort_t* __restrict__ ow2t)
{
    int t = blockIdx.x * 256 + threadIdx.x;
    const int S0 = 3 * HID * K1PAD, S1 = 3 * EMB * K2PAD;
    const int S2 = 3 * HID * K2PAD, S3 = 3 * EMB * K2PAD;
    const int S4 = HID * EKP, S5 = EMB * K2PAD;
    const int S6 = HID * XKP, S7 = EMB * K2PAD;
    if (t < S0) {   // msg_w1 [l][136][128] -> [l][c=128][k=148]
        int l = t / (HID * K1PAD), r = t % (HID * K1PAD), c = r / K1PAD, k = r % K1PAD;
        mw1t[t] = f2bf(k < CAT ? msg_w1[(size_t)l * CAT * HID + (size_t)k * HID + c] : 0.f);
        return;
    } t -= S0;
    if (t < S1) {   // msg_w2 [l][128][64] -> [l][c=64][k=140]
        int l = t / (EMB * K2PAD), r = t % (EMB * K2PAD), c = r / K2PAD, k = r % K2PAD;
        mw2t[t] = f2bf(k < HID ? msg_w2[(size_t)l * HID * EMB + (size_t)k * EMB + c] : 0.f);
        return;
    } t -= S1;
    if (t < S2) {   // upd_w1 [l][128][128] -> [l][c=128][k=140]
        int l = t / (HID * K2PAD), r = t % (HID * K2PAD), c = r / K2PAD, k = r % K2PAD;
        uw1t[t] = f2bf(k < 2 * EMB ? upd_w1[(size_t)l * 2 * EMB * HID + (size_t)k * HID + c] : 0.f);
        return;
    } t -= S2;
    if (t < S3) {   // upd_w2 [l][128][64] -> [l][c=64][k=140]
        int l = t / (EMB * K2PAD), r = t % (EMB * K2PAD), c = r / K2PAD, k = r % K2PAD;
        uw2t[t] = f2bf(k < HID ? upd_w2[(size_t)l * HID * EMB + (size_t)k * EMB + c] : 0.f);
        return;
    } t -= S3;
    if (t < S4) {   // enc_w1 [25][128] -> [c=128][k=36]
        int c = t / EKP, k = t % EKP;
        ew1t[t] = f2bf(k < OBS ? enc_w1[(size_t)k * HID + c] : 0.f);
        return;
    } t -= S4;
    if (t < S5) {   // enc_w2 [128][64] -> [c=64][k=140]
        int c = t / K2PAD, k = t % K2PAD;
        ew2t[t] = f2bf(k < HID ? enc_w2[(size_t)k * EMB + c] : 0.f);
        return;
    } t -= S5;
    if (t < S6) {   // out_w1 [64][128] -> [c=128][k=68]
        int c = t / XKP, k = t % XKP;
        ow1t[t] = f2bf(k < EMB ? out_w1[(size_t)k * HID + c] : 0.f);
        return;
    } t -= S6;
    if (t < S7) {   // out_w2 [128][64] -> [c=64][k=140]
        int c = t / K2PAD, k = t % K2PAD;
        ow2t[t] = f2bf(k < HID ? out_w2[(size_t)k * EMB + c] : 0.f);
    }
}

// ================= MFMA encoder (TB=64, weights from global) ================
__global__ __launch_bounds__(256, 2) void k_encoder_mfma(
    const float* __restrict__ obs,
    const ushort_t* __restrict__ w1t, const float* __restrict__ b1,
    const float* __restrict__ lng, const float* __restrict__ lnb,
    const ushort_t* __restrict__ w2t, const float* __restrict__ b2,
    float* __restrict__ x, ushort_t* __restrict__ xb, int n)
{
    __shared__ __align__(16) ushort_t s_OB[TBN * EKP];     //  4608 B
    __shared__ __align__(16) float    s_G[TBN * 132];      // 33792 B
    __shared__ __align__(16) ushort_t s_H[TBN * K2PAD];    // 17920 B

    const int tid = threadIdx.x;
    const int lane = tid & 63, wid = tid >> 6;
    const int wr = wid >> 1, wc2 = wid & 1;     // GEMM1 mapping
    const int wr2 = wid & 1, wc3 = wid >> 1;    // GEMM2 mapping
    const int l31 = lane & 31, lhi = lane >> 5;
    const int n0 = blockIdx.x * TBN;

    for (int i = tid; i < TBN * 32; i += 256) {
        int row = i >> 5, k = i & 31;
        int gn = n0 + row;
        s_OB[row * EKP + k] = f2bf((gn < n && k < OBS) ? obs[(size_t)gn * OBS + k] : 0.f);
    }
    __syncthreads();

    // GEMM1: [64 x 32] @ [32 x 128], B from global
    f32x16 a0, a1;
    {
        float bv0 = b1[wc2 * 64 + l31], bv1 = b1[wc2 * 64 + 32 + l31];
#pragma unroll
        for (int i = 0; i < 16; ++i) { a0[i] = bv0; a1[i] = bv1; }
    }
    {
        const ushort_t* aR = s_OB + (wr * 32 + l31) * EKP;
        const ushort_t* bR0 = w1t + (wc2 * 64 + l31) * EKP;
        const ushort_t* bR1 = bR0 + 32 * EKP;
        const int koff = lhi * 8;
#pragma unroll
        for (int s = 0; s < 2; ++s) {
            const int ke = s * 16 + koff;
            bf16x8 av = ld8(aR + ke);
            bf16x8 bv0 = ld8(bR0 + ke), bv1 = ld8(bR1 + ke);
            a0 = __builtin_amdgcn_mfma_f32_32x32x16_bf16(av, bv0, a0, 0, 0, 0);
            a1 = __builtin_amdgcn_mfma_f32_32x32x16_bf16(av, bv1, a1, 0, 0, 0);
        }
    }
    {
#pragma unroll
        for (int r = 0; r < 16; ++r) {
            int row = wr * 32 + CROW(r, lhi);
            s_G[row * 132 + wc2 * 64 + l31] = a0[r];
            s_G[row * 132 + wc2 * 64 + 32 + l31] = a1[r];
        }
    }
    __syncthreads();

    // LN + relu -> bf16 H
    if (tid < TBN) {
        float sum = 0.f, sum2 = 0.f;
        const float* gr = s_G + tid * 132;
#pragma unroll 8
        for (int q = 0; q < HID; ++q) { float v = gr[q]; sum += v; sum2 += v * v; }
        float mu = sum * (1.f / HID);
        float var = fmaxf(sum2 * (1.f / HID) - mu * mu, 0.f);
        float rs = 1.f / sqrtf(var + 1e-5f);
        ushort_t* hr = s_H + tid * K2PAD;
#pragma unroll 8
        for (int q = 0; q < HID; ++q) {
            float v = (gr[q] - mu) * rs * lng[q] + lnb[q];
            hr[q] = f2bf(fmaxf(v, 0.f));
        }
    }
    __syncthreads();

    // GEMM2: [64 x 128] @ [128 x 64], B from global
    f32x16 c0;
    {
        float bv = b2[wc3 * 32 + l31];
#pragma unroll
        for (int i = 0; i < 16; ++i) c0[i] = bv;
    }
    {
        const ushort_t* aR = s_H + (wr2 * 32 + l31) * K2PAD;
        const ushort_t* bR = w2t + (wc3 * 32 + l31) * K2PAD;
        const int koff = lhi * 8;
#pragma unroll
        for (int s = 0; s < K2STEPS; ++s) {
            const int ke = s * 16 + koff;
            bf16x8 av = ld8(aR + ke);
            bf16x8 bv = ld8(bR + ke);
            c0 = __builtin_amdgcn_mfma_f32_32x32x16_bf16(av, bv, c0, 0, 0, 0);
        }
    }
    {
        const int col = wc3 * 32 + l31;
#pragma unroll
        for (int r = 0; r < 16; ++r) {
            int g = n0 + wr2 * 32 + CROW(r, lhi);
            if (g < n) {
                float v = fmaxf(c0[r], 0.f);
                x[(size_t)g * EMB + col] = v;
                xb[(size_t)g * EMB + col] = f2bf(v);
            }
        }
    }
}

// ================= MFMA edge layer (r10 banked version, unchanged) ==========
__global__ __launch_bounds__(ETHR, 8) void k_edge_mfma(
    const ushort_t* __restrict__ xb,
    const uint4v* __restrict__ eab4,
    const ushort_t* __restrict__ w1t,
    const float* __restrict__ b1,
    const ushort_t* __restrict__ w2t,
    const float* __restrict__ b2,
    float* __restrict__ aggr, int ne)
{
    __shared__ __align__(16) ushort_t s_A[TE * K1PAD];
    __shared__ int s_dst[TE];
    ushort_t* s_H = s_A;
    float*    s_M = reinterpret_cast<float*>(s_A);

    const int tid  = threadIdx.x;
    const int lane = tid & 63, wid = tid >> 6;
    const int wr = wid >> 1, wc = wid & 1;
    const int l31 = lane & 31, lhi = lane >> 5;
    const int e0 = blockIdx.x * TE;

    {
        const int e = tid >> 2, h = tid & 3, ge = e0 + e;
        ushort_t* arow = s_A + e * K1PAD;
        uint4v ev = eab4[ge];
        if (h == 0) {
            s_dst[e] = (int)ev.w;
            const uint2* sp = reinterpret_cast<const uint2*>(xb + (size_t)ev.w * EMB);
            uint2* dp = reinterpret_cast<uint2*>(arow);
#pragma unroll
            for (int i = 0; i < 8; ++i) dp[i] = sp[i];
        } else if (h == 1) {
            const uint2* sp = reinterpret_cast<const uint2*>(xb + (size_t)ev.w * EMB) + 8;
            uint2* dp = reinterpret_cast<uint2*>(arow) + 8;
#pragma unroll
            for (int i = 0; i < 8; ++i) dp[i] = sp[i];
        } else if (h == 2) {
            const uint2* sp = reinterpret_cast<const uint2*>(xb + (size_t)ev.z * EMB);
            uint2* dp = reinterpret_cast<uint2*>(arow + EMB);
#pragma unroll
            for (int i = 0; i < 8; ++i) dp[i] = sp[i];
        } else {
            const uint2* sp = reinterpret_cast<const uint2*>(xb + (size_t)ev.z * EMB) + 8;
            uint2* dp = reinterpret_cast<uint2*>(arow + EMB) + 8;
#pragma unroll
            for (int i = 0; i < 8; ++i) dp[i] = sp[i];
            uint_t dn_b = ev.x & 0xFFFFu, rxn_b = ev.x >> 16;
            uint_t ryn_b = ev.y & 0xFFFFu, flag = ev.y >> 16;
            uint_t cos_b = flag ? 0x3F80u : rxn_b;
            uint_t sin_b = flag ? 0u : ryn_b;
            union { uint_t u; float f; } cv; cv.u = dn_b << 16;
            uint_t dn2_b = (uint_t)f2bf(cv.f * cv.f);
            uint2* ap = reinterpret_cast<uint2*>(arow + 2 * EMB);
            ap[0] = make_uint2(dn_b | (rxn_b << 16), ryn_b | (cos_b << 16));
            ap[1] = make_uint2(sin_b | (dn2_b << 16), 0u);
            uint2* pp = reinterpret_cast<uint2*>(arow + CAT);
            pp[0] = make_uint2(0u, 0u); pp[1] = make_uint2(0u, 0u);
            pp[2] = make_uint2(0u, 0u);
        }
    }
    __syncthreads();

    f32x16 a0, a1;
    {
        float bv0 = b1[wc * 64 + l31], bv1 = b1[wc * 64 + 32 + l31];
#pragma unroll
        for (int i = 0; i < 16; ++i) { a0[i] = bv0; a1[i] = bv1; }
    }
    {
        const ushort_t* aR = s_A + (wr * 32 + l31) * K1PAD;
        const ushort_t* bR0 = w1t + (wc * 64 + l31) * K1PAD;
        const ushort_t* bR1 = bR0 + 32 * K1PAD;
        const int koff = lhi * 8;
#pragma unroll
        for (int s = 0; s < K1STEPS; ++s) {
            const int ke = s * 16 + koff;
            bf16x8 av = ld8(aR + ke);
            bf16x8 bv0 = ld8(bR0 + ke);
            bf16x8 bv1 = ld8(bR1 + ke);
            a0 = __builtin_amdgcn_mfma_f32_32x32x16_bf16(av, bv0, a0, 0, 0, 0);
            a1 = __builtin_amdgcn_mfma_f32_32x32x16_bf16(av, bv1, a1, 0, 0, 0);
        }
    }
    __syncthreads();

#define WRITE_HE(ACC, NC)                                                      \
    {                                                                          \
        const int col = wc * 64 + (NC) * 32 + l31;                             \
        _Pragma("unroll")                                                      \
        for (int r = 0; r < 16; ++r) {                                         \
            int row = wr * 32 + CROW(r, lhi);                                  \
            s_H[row * K2PAD + col] = f2bf(fmaxf(ACC[r], 0.f));                 \
        }                                                                      \
    }
    WRITE_HE(a0, 0) WRITE_HE(a1, 1)
#undef WRITE_HE
    __syncthreads();

    f32x16 c0;
    {
        float bv = b2[wc * 32 + l31];
#pragma unroll
        for (int i = 0; i < 16; ++i) c0[i] = bv;
    }
    {
        const ushort_t* aR = s_H + (wr * 32 + l31) * K2PAD;
        const ushort_t* bR = w2t + (wc * 32 + l31) * K2PAD;
        const int koff = lhi * 8;
#pragma unroll
        for (int s = 0; s < K2STEPS; ++s) {
            const int ke = s * 16 + koff;
            bf16x8 av = ld8(aR + ke);
            bf16x8 bv = ld8(bR + ke);
            c0 = __builtin_amdgcn_mfma_f32_32x32x16_bf16(av, bv, c0, 0, 0, 0);
        }
    }
    __syncthreads();

    {
        const int col = wc * 32 + l31;
#pragma unroll
        for (int r = 0; r < 16; ++r) {
            int row = wr * 32 + CROW(r, lhi);
            s_M[row * 68 + col] = c0[r] * 0.25f;
        }
    }
    __syncthreads();

    if (tid < 256) {
        const int col = tid & 63, g = tid >> 6, base = g * 32;
        int cur = s_dst[base];
        float acc = 0.f;
#pragma unroll 8
        for (int r = 0; r < 32; ++r) {
            int d = s_dst[base + r];
            float v = s_M[(base + r) * 68 + col];
            if (d != cur) {
                atomicAdd(aggr + (size_t)cur * EMB + col, acc);
                acc = 0.f; cur = d;
            }
            acc += v;
        }
        atomicAdd(aggr + (size_t)cur * EMB + col, acc);
    }
}

// ================= MFMA node update (TB=64, weights global, fused output) ===
// x = LN(x + relu([x,aggr]@W1+b1)@W2+b2); if fuse: out = relu(x@OW1+ob1)@OW2+ob2
__global__ __launch_bounds__(256, 4) void k_update_mfma(
    float* __restrict__ x, ushort_t* __restrict__ xb,
    float* __restrict__ aggr,
    const ushort_t* __restrict__ w1t, const float* __restrict__ b1,
    const ushort_t* __restrict__ w2t, const float* __restrict__ b2,
    const float* __restrict__ g, const float* __restrict__ bb,
    const ushort_t* __restrict__ ow1t, const float* __restrict__ ob1,
    const ushort_t* __restrict__ ow2t, const float* __restrict__ ob2,
    float* __restrict__ out, int fuse, int n)
{
    __shared__ __align__(16) ushort_t s_big[TBN * K2PAD];  // A / H / U overlay
    __shared__ __align__(16) ushort_t s_Xn[TBN * XKP];     // fused-out A (bf16 x)
    ushort_t* s_A = s_big;
    ushort_t* s_H = s_big;
    float*    s_U = reinterpret_cast<float*>(s_big);       // [64][68] fp32

    const int tid = threadIdx.x;
    const int lane = tid & 63, wid = tid >> 6;
    const int wr = wid >> 1, wc2 = wid & 1;
    const int wr2 = wid & 1, wc3 = wid >> 1;
    const int l31 = lane & 31, lhi = lane >> 5;
    const int n0 = blockIdx.x * TBN;

    // ---- stage A rows: [xb | bf(aggr)], 4 threads/row; zero aggr for reuse --
    {
        const int row = tid >> 2, h = tid & 3;
        const int gn = n0 + row;
        ushort_t* arow = s_A + row * K2PAD;
        if (h < 2) {
            uint2* dp = reinterpret_cast<uint2*>(arow) + h * 8;
            if (gn < n) {
                const uint2* sp = reinterpret_cast<const uint2*>(xb + (size_t)gn * EMB) + h * 8;
#pragma unroll
                for (int i = 0; i < 8; ++i) dp[i] = sp[i];
            } else {
                const uint2 z = make_uint2(0u, 0u);
#pragma unroll
                for (int i = 0; i < 8; ++i) dp[i] = z;
            }
        } else {
            const int hh = h - 2;
            uint_t* dp32 = reinterpret_cast<uint_t*>(arow + EMB + hh * 32);
            if (gn < n) {
                float4* sp = reinterpret_cast<float4*>(aggr + (size_t)gn * EMB + hh * 32);
                const float4 z4 = make_float4(0.f, 0.f, 0.f, 0.f);
#pragma unroll
                for (int i = 0; i < 8; ++i) {
                    float4 v = sp[i];
                    sp[i] = z4;                  // zero for next layer's atomics
                    dp32[2 * i]     = (uint_t)f2bf(v.x) | ((uint_t)f2bf(v.y) << 16);
                    dp32[2 * i + 1] = (uint_t)f2bf(v.z) | ((uint_t)f2bf(v.w) << 16);
                }
            } else {
#pragma unroll
                for (int i = 0; i < 16; ++i) dp32[i] = 0u;
            }
        }
    }
    __syncthreads();

    // ---- GEMM1: [64 x 128] @ [128 x 128], B from global ----
    f32x16 a0, a1;
    {
        float bv0 = b1[wc2 * 64 + l31], bv1 = b1[wc2 * 64 + 32 + l31];
#pragma unroll
        for (int i = 0; i < 16; ++i) { a0[i] = bv0; a1[i] = bv1; }
    }
    {
        const ushort_t* aR = s_A + (wr * 32 + l31) * K2PAD;
        const ushort_t* bR0 = w1t + (wc2 * 64 + l31) * K2PAD;
        const ushort_t* bR1 = bR0 + 32 * K2PAD;
        const int koff = lhi * 8;
#pragma unroll
        for (int s = 0; s < K2STEPS; ++s) {
            const int ke = s * 16 + koff;
            bf16x8 av = ld8(aR + ke);
            bf16x8 bv0 = ld8(bR0 + ke), bv1 = ld8(bR1 + ke);
            a0 = __builtin_amdgcn_mfma_f32_32x32x16_bf16(av, bv0, a0, 0, 0, 0);
            a1 = __builtin_amdgcn_mfma_f32_32x32x16_bf16(av, bv1, a1, 0, 0, 0);
        }
    }
    __syncthreads();

    // ---- relu -> bf16 H (overlay A) ----
#define WRITE_HU(ACC, NC)                                                      \
    {                                                                          \
        const int col = wc2 * 64 + (NC) * 32 + l31;                            \
        _Pragma("unroll")                                                      \
        for (int r = 0; r < 16; ++r) {                                         \
            int row = wr * 32 + CROW(r, lhi);                                  \
            s_H[row * K2PAD + col] = f2bf(fmaxf(ACC[r], 0.f));                 \
        }                                                                      \
    }
    WRITE_HU(a0, 0) WRITE_HU(a1, 1)
    __syncthreads();

    // ---- GEMM2: [64 x 128] @ [128 x 64], B from global ----
    f32x16 c0;
    {
        float bv = b2[wc3 * 32 + l31];
#pragma unroll
        for (int i = 0; i < 16; ++i) c0[i] = bv;
    }
    {
        const ushort_t* aR = s_H + (wr2 * 32 + l31) * K2PAD;
        const ushort_t* bR = w2t + (wc3 * 32 + l31) * K2PAD;
        const int koff = lhi * 8;
#pragma unroll
        for (int s = 0; s < K2STEPS; ++s) {
            const int ke = s * 16 + koff;
            bf16x8 av = ld8(aR + ke);
            bf16x8 bv = ld8(bR + ke);
            c0 = __builtin_amdgcn_mfma_f32_32x32x16_bf16(av, bv, c0, 0, 0, 0);
        }
    }
    __syncthreads();

    // ---- U (fp32) overlay ----
    {
        const int col = wc3 * 32 + l31;
#pragma unroll
        for (int r = 0; r < 16; ++r) {
            int row = wr2 * 32 + CROW(r, lhi);
            s_U[row * 68 + col] = c0[r];
        }
    }
    __syncthreads();

    if (!fuse) {
        // ---- LN(x + U) -> x, xb ----
        if (tid < TBN) {
            int gn = n0 + tid;
            if (gn < n) {
                const float* xr = x + (size_t)gn * EMB;
                float* ur = s_U + tid * 68;
                float sum = 0.f, sum2 = 0.f;
#pragma unroll 8
                for (int q = 0; q < EMB; ++q) {
                    float v = xr[q] + ur[q];
                    ur[q] = v;
                    sum += v; sum2 += v * v;
                }
                float mu = sum * (1.f / EMB);
                float var = fmaxf(sum2 * (1.f / EMB) - mu * mu, 0.f);
                float rs = 1.f / sqrtf(var + 1e-5f);
                float* xo = x + (size_t)gn * EMB;
                ushort_t* xbo = xb + (size_t)gn * EMB;
#pragma unroll 8
                for (int q = 0; q < EMB; ++q) {
                    float v = (ur[q] - mu) * rs * g[q] + bb[q];
                    xo[q] = v;
                    xbo[q] = f2bf(v);
                }
            }
        }
        return;
    }

    // ---- fused final layer: LN -> s_Xn (bf16), then output projection ----
    if (tid < TBN) {
        int gn = n0 + tid;
        if (gn < n) {
            const float* xr = x + (size_t)gn * EMB;
            const float* ur = s_U + tid * 68;
            float sum = 0.f, sum2 = 0.f;
#pragma unroll 8
            for (int q = 0; q < EMB; ++q) {
                float v = xr[q] + ur[q];
                sum += v; sum2 += v * v;
            }
            float mu = sum * (1.f / EMB);
            float var = fmaxf(sum2 * (1.f / EMB) - mu * mu, 0.f);
            float rs = 1.f / sqrtf(var + 1e-5f);
            ushort_t* xnr = s_Xn + tid * XKP;
#pragma unroll 8
            for (int q = 0; q < EMB; ++q) {
                float v = (xr[q] + ur[q] - mu) * rs * g[q] + bb[q];
                xnr[q] = f2bf(v);
            }
        }
    }
    __syncthreads();

    // GEMM1-out: [64 x 64] @ [64 x 128], A = s_Xn, B from global
    f32x16 o0, o1;
    {
        float bv0 = ob1[wc2 * 64 + l31], bv1 = ob1[wc2 * 64 + 32 + l31];
#pragma unroll
        for (int i = 0; i < 16; ++i) { o0[i] = bv0; o1[i] = bv1; }
    }
    {
        const ushort_t* aR = s_Xn + (wr * 32 + l31) * XKP;
        const ushort_t* bR0 = ow1t + (wc2 * 64 + l31) * XKP;
        const ushort_t* bR1 = bR0 + 32 * XKP;
        const int koff = lhi * 8;
#pragma unroll
        for (int s = 0; s < 4; ++s) {
            const int ke = s * 16 + koff;
            bf16x8 av = ld8(aR + ke);
            bf16x8 bv0 = ld8(bR0 + ke), bv1 = ld8(bR1 + ke);
            o0 = __builtin_amdgcn_mfma_f32_32x32x16_bf16(av, bv0, o0, 0, 0, 0);
            o1 = __builtin_amdgcn_mfma_f32_32x32x16_bf16(av, bv1, o1, 0, 0, 0);
        }
    }
    // relu -> H over big buffer (U dead after LN barrier)
    WRITE_HU(o0, 0) WRITE_HU(o1, 1)
#undef WRITE_HU
    __syncthreads();

    // GEMM2-out: [64 x 128] @ [128 x 64] -> store out
    f32x16 q0;
    {
        float bv = ob2[wc3 * 32 + l31];
#pragma unroll
        for (int i = 0; i < 16; ++i) q0[i] = bv;
    }
    {
        const ushort_t* aR = s_H + (wr2 * 32 + l31) * K2PAD;
        const ushort_t* bR = ow2t + (wc3 * 32 + l31) * K2PAD;
        const int koff = lhi * 8;
#pragma unroll
        for (int s = 0; s < K2STEPS; ++s) {
            const int ke = s * 16 + koff;
            bf16x8 av = ld8(aR + ke);
            bf16x8 bv = ld8(bR + ke);
            q0 = __builtin_amdgcn_mfma_f32_32x32x16_bf16(av, bv, q0, 0, 0, 0);
        }
    }
    {
        const int col = wc3 * 32 + l31;
#pragma unroll
        for (int r = 0; r < 16; ++r) {
            int grow = n0 + wr2 * 32 + CROW(r, lhi);
            if (grow < n) out[(size_t)grow * EMB + col] = q0[r];
        }
    }
}

extern "C" void kernel_launch(void* const* d_in, const int* in_sizes, int n_in,
                              void* d_out, int out_size, void* d_ws, size_t ws_size,
                              hipStream_t stream)
{
    const float* obs     = (const float*)d_in[0];
    const float* pos     = (const float*)d_in[1];
    const int*   eidx    = (const int*)d_in[2];
    const float* enc_w1  = (const float*)d_in[3];
    const float* enc_b1  = (const float*)d_in[4];
    const float* enc_lng = (const float*)d_in[5];
    const float* enc_lnb = (const float*)d_in[6];
    const float* enc_w2  = (const float*)d_in[7];
    const float* enc_b2  = (const float*)d_in[8];
    const float* msg_w1  = (const float*)d_in[9];
    const float* msg_b1  = (const float*)d_in[10];
    const float* msg_w2  = (const float*)d_in[11];
    const float* msg_b2  = (const float*)d_in[12];
    // d_in[13..16] = att_* : mathematically unused (mean(softmax) == 0.25)
    const float* upd_w1  = (const float*)d_in[17];
    const float* upd_b1  = (const float*)d_in[18];
    const float* upd_w2  = (const float*)d_in[19];
    const float* upd_b2  = (const float*)d_in[20];
    const float* ln_g    = (const float*)d_in[21];
    const float* ln_b    = (const float*)d_in[22];
    const float* out_w1  = (const float*)d_in[23];
    const float* out_b1  = (const float*)d_in[24];
    const float* out_w2  = (const float*)d_in[25];
    const float* out_b2  = (const float*)d_in[26];

    const int n  = in_sizes[0] / OBS;   // 50000
    const int ne = in_sizes[2] / 2;     // 800000
    const int* src = eidx;
    const int* dst = eidx + ne;

    char* ws = (char*)d_ws;
    float*    x     = (float*)ws;                          // 12,800,000 B
    ushort_t* xbuf  = (ushort_t*)(ws + 12800000);          //  6,400,000 B
    uint4v*   eab4  = (uint4v*)(ws + 19200000);            // 12,800,000 B
    float*    aggr  = (float*)(ws + 32000000);             // 12,800,000 B
    ushort_t* mw1t  = (ushort_t*)(ws + 44800000);          //    113,664 B
    ushort_t* mw2t  = (ushort_t*)(ws + 44913664);          //     53,760 B
    ushort_t* uw1t  = (ushort_t*)(ws + 44967424);          //    107,520 B
    ushort_t* uw2t  = (ushort_t*)(ws + 45074944);          //     53,760 B
    ushort_t* ew1t  = (ushort_t*)(ws + 45128704);          //      9,216 B
    ushort_t* ew2t  = (ushort_t*)(ws + 45137920);          //     17,920 B
    ushort_t* ow1t  = (ushort_t*)(ws + 45155840);          //     17,408 B
    ushort_t* ow2t  = (ushort_t*)(ws + 45173248);          //     17,920 B
    int*      hist  = (int*)(ws + 45191168);               //    200,000 B
    int*      scan  = (int*)(ws + 45391168);               //    200,000 B
    int*      bsum  = (int*)(ws + 45591168);               //        512 B
    // total ~45.6 MB (< 51.2 MB proven safe)

    const int NB1 = (NN + 511) / 512;     // 98
    const int nbN = (n + TBN - 1) / TBN;  // 782
    const int PREP_TOTAL = 3 * HID * K1PAD + 3 * EMB * K2PAD + 3 * HID * K2PAD
                         + 3 * EMB * K2PAD + HID * EKP + EMB * K2PAD
                         + HID * XKP + EMB * K2PAD;        // 195,584

    // ---- counting sort of edges by dst (+ fused edge features) ----
    hipMemsetAsync(hist, 0, NN * sizeof(int), stream);
    k_hist<<<(ne + 255) / 256, 256, 0, stream>>>(dst, hist, ne);
    k_scan1<<<NB1, 512, 0, stream>>>(hist, scan, bsum, NN);
    k_scan3<<<NB1, 512, 0, stream>>>(scan, bsum, NN);
    k_scatter_feat<<<(ne + 255) / 256, 256, 0, stream>>>(pos, src, dst, scan,
                                                         eab4, ne);

    k_prep_all<<<(PREP_TOTAL + 255) / 256, 256, 0, stream>>>(
        msg_w1, msg_w2, upd_w1, upd_w2, enc_w1, enc_w2, out_w1, out_w2,
        mw1t, mw2t, uw1t, uw2t, ew1t, ew2t, ow1t, ow2t);
    k_encoder_mfma<<<nbN, 256, 0, stream>>>(obs, ew1t, enc_b1, enc_lng, enc_lnb,
                                            ew2t, enc_b2, x, xbuf, n);
    // aggr zeroed once here; k_update re-zeroes it for the next layer.
    hipMemsetAsync(aggr, 0, (size_t)n * EMB * sizeof(float), stream);

    for (int l = 0; l < 3; ++l) {
        k_edge_mfma<<<ne / TE, ETHR, 0, stream>>>(
            xbuf, eab4,
            mw1t + (size_t)l * HID * K1PAD, msg_b1 + (size_t)l * HID,
            mw2t + (size_t)l * EMB * K2PAD, msg_b2 + (size_t)l * EMB,
            aggr, ne);
        k_update_mfma<<<nbN, 256, 0, stream>>>(
            x, xbuf, aggr,
            uw1t + (size_t)l * HID * K2PAD, upd_b1 + (size_t)l * HID,
            uw2t + (size_t)l * EMB * K2PAD, upd_b2 + (size_t)l * EMB,
            ln_g + (size_t)l * EMB, ln_b + (size_t)l * EMB,
            ow1t, out_b1, ow2t, out_b2,
            (float*)d_out, (l == 2) ? 1 : 0, n);
    }
}